// Round 1
// baseline (2644.988 us; speedup 1.0000x reference)
//
#include <hip/hip_runtime.h>
#include <hip/hip_bf16.h>
#include <math.h>

#define B_   2
#define T_   1024
#define HID_ 2048
#define H_   16
#define DK_  128
#define DV_  128
#define TS_  16     // timesteps staged per LDS tile in recurrence

__device__ __forceinline__ float sigmoidf_(float x) {
    return 1.0f / (1.0f + __expf(-x));
}

// ---------------------------------------------------------------------------
// Generic fp32 GEMM: C[M,N] = A[M,K] @ B[K,N] (+ bias). 64x64 tile, BK=16,
// 256 threads, 4x4 per thread. M % 64 == 0 and K % 16 == 0 assumed (true for
// all calls here); N may be < 64 (guarded path).
// ---------------------------------------------------------------------------
__global__ __launch_bounds__(256) void sgemm_kernel(
    const float* __restrict__ A, const float* __restrict__ B,
    const float* __restrict__ bias, float* __restrict__ C,
    int M, int N, int K)
{
    __shared__ float As[16][64];   // transposed: As[k][m]
    __shared__ float Bs[16][64];   // Bs[k][n]

    const int tid  = threadIdx.x;
    const int n0   = blockIdx.x * 64;
    const int m0   = blockIdx.y * 64;
    const bool fullN = (n0 + 64 <= N);

    const int arow = tid >> 2;          // 0..63
    const int acol = (tid & 3) << 2;    // 0,4,8,12
    const int brow = tid >> 4;          // 0..15
    const int bcol = (tid & 15) << 2;   // 0..60
    const int tr   = tid >> 4;          // 0..15 (row group)
    const int tc   = tid & 15;          // 0..15 (col group)

    float acc[4][4];
    #pragma unroll
    for (int i = 0; i < 4; ++i)
        #pragma unroll
        for (int j = 0; j < 4; ++j) acc[i][j] = 0.0f;

    for (int k0 = 0; k0 < K; k0 += 16) {
        float4 a4 = *(const float4*)(A + (size_t)(m0 + arow) * K + k0 + acol);
        float4 b4;
        if (fullN) {
            b4 = *(const float4*)(B + (size_t)(k0 + brow) * N + n0 + bcol);
        } else {
            const float* Bp = B + (size_t)(k0 + brow) * N;
            b4.x = (n0 + bcol + 0 < N) ? Bp[n0 + bcol + 0] : 0.0f;
            b4.y = (n0 + bcol + 1 < N) ? Bp[n0 + bcol + 1] : 0.0f;
            b4.z = (n0 + bcol + 2 < N) ? Bp[n0 + bcol + 2] : 0.0f;
            b4.w = (n0 + bcol + 3 < N) ? Bp[n0 + bcol + 3] : 0.0f;
        }
        __syncthreads();
        As[acol + 0][arow] = a4.x;
        As[acol + 1][arow] = a4.y;
        As[acol + 2][arow] = a4.z;
        As[acol + 3][arow] = a4.w;
        *(float4*)&Bs[brow][bcol] = b4;
        __syncthreads();
        #pragma unroll
        for (int kk = 0; kk < 16; ++kk) {
            float4 av = *(const float4*)&As[kk][tr << 2];
            float4 bv = *(const float4*)&Bs[kk][tc << 2];
            float ar[4] = {av.x, av.y, av.z, av.w};
            float br[4] = {bv.x, bv.y, bv.z, bv.w};
            #pragma unroll
            for (int i = 0; i < 4; ++i)
                #pragma unroll
                for (int j = 0; j < 4; ++j)
                    acc[i][j] += ar[i] * br[j];
        }
    }

    #pragma unroll
    for (int i = 0; i < 4; ++i) {
        int row = m0 + (tr << 2) + i;
        #pragma unroll
        for (int j = 0; j < 4; ++j) {
            int colg = n0 + (tc << 2) + j;
            if (colg < N) {
                float r = acc[i][j];
                if (bias) r += bias[colg];
                C[(size_t)row * N + colg] = r;
            }
        }
    }
}

// ---------------------------------------------------------------------------
// Causal depthwise conv1d (K=4) + SiLU, optional per-head l2norm (+q scale).
// One block per (b,t); 256 threads x 8 channels each (c = tid + 256*jj).
// mode: 0 = silu only (v); 1 = + l2norm (k); 2 = + l2norm * DK^-0.5 (q)
// ---------------------------------------------------------------------------
__global__ __launch_bounds__(256) void conv_silu_kernel(
    const float* __restrict__ xin, const float* __restrict__ w,
    float* __restrict__ yout, int mode)
{
    const int bt  = blockIdx.x;       // b*T + t
    const int t   = bt & (T_ - 1);
    const int tid = threadIdx.x;
    const size_t row = (size_t)bt * HID_;

    float val[8];
    #pragma unroll
    for (int jj = 0; jj < 8; ++jj) {
        int c = tid + 256 * jj;
        float4 wc = *(const float4*)(w + (size_t)c * 4);   // w[c][0..3]
        const float* xc = xin + row + c;
        float acc = wc.w * xc[0];                          // tap i=3 -> x[t]
        if (t >= 1) acc += wc.z * xc[-HID_];
        if (t >= 2) acc += wc.y * xc[-2 * HID_];
        if (t >= 3) acc += wc.x * xc[-3 * HID_];
        val[jj] = acc * sigmoidf_(acc);                    // SiLU
    }

    if (mode > 0) {
        __shared__ float red[4][8];
        const int wv = tid >> 6;
        #pragma unroll
        for (int jj = 0; jj < 8; ++jj) {
            float v2 = val[jj] * val[jj];
            #pragma unroll
            for (int m = 1; m < 64; m <<= 1) v2 += __shfl_xor(v2, m);
            if ((tid & 63) == 0) red[wv][jj] = v2;
        }
        __syncthreads();
        const int wb = (tid >> 7) * 2;   // wave-pair contributing to my heads
        #pragma unroll
        for (int jj = 0; jj < 8; ++jj) {
            float ss = red[wb][jj] + red[wb + 1][jj];
            float sc = rsqrtf(ss + 1e-6f);
            if (mode == 2) sc *= 0.08838834764831845f;     // DK^-0.5
            val[jj] *= sc;
        }
    }

    #pragma unroll
    for (int jj = 0; jj < 8; ++jj)
        yout[row + tid + 256 * jj] = val[jj];
}

// ---------------------------------------------------------------------------
// Decay gates: in-place  gb <- exp(gf), gd <- exp(gs)
// gf = -exp(A_log[h]) * softplus(gb + gd + dtb), gs with (gb - gd).
// ---------------------------------------------------------------------------
__global__ __launch_bounds__(256) void decay_gate_kernel(
    float* gb, float* gd,
    const float* __restrict__ A_log, const float* __restrict__ dt_bias)
{
    size_t i = (size_t)blockIdx.x * 256 + threadIdx.x;  // over B*T*H*DK
    int c = (int)(i & (HID_ - 1));
    int h = c >> 7;
    float a  = gb[i];
    float d  = gd[i];
    float na = -__expf(A_log[h]);
    float db = dt_bias[c];
    float xf = a + d + db;
    float xs = a - d + db;
    float spf = (xf > 20.0f) ? xf : log1pf(__expf(xf));
    float sps = (xs > 20.0f) ? xs : log1pf(__expf(xs));
    gb[i] = __expf(na * spf);
    gd[i] = __expf(na * sps);
}

// ---------------------------------------------------------------------------
// Dual-state gated delta-rule recurrence. One block per (b,h,s,vchunk of 32
// DV-columns): grid = 2*16*2*4 = 256 blocks, 256 threads.
// Wave layout: lane = col8*8 + kseg  (8 columns x 8 k-segments of 16).
// Each thread owns S[16] (its 16 k's of one column). Per-column reductions
// are 3 shfl_xor's. q/k/exp(g)/v/beta staged in LDS 16 timesteps at a time.
// ---------------------------------------------------------------------------
__global__ __launch_bounds__(256) void fkda_kernel(
    const float* __restrict__ qp, const float* __restrict__ kp,
    const float* __restrict__ vp, const float* __restrict__ egf,
    const float* __restrict__ egs, const float* __restrict__ bbp,
    const float* __restrict__ bdp,
    float* __restrict__ ofp, float* __restrict__ osp)
{
    const int bx = blockIdx.x;
    const int vc = bx & 3;
    const int s  = (bx >> 2) & 1;
    const int h  = (bx >> 3) & 15;
    const int b  = bx >> 7;

    const float* eg = s ? egs : egf;
    float*       op = s ? osp : ofp;
    const float  bsign = s ? -1.0f : 1.0f;

    const int tid  = threadIdx.x;
    const int lane = tid & 63;
    const int wv   = tid >> 6;
    const int kseg = lane & 7;              // 16 k's each
    const int col  = wv * 8 + (lane >> 3);  // 0..31 within chunk

    const size_t base = (size_t)b * T_ * HID_ + (size_t)h * DK_;  // + t*2048

    __shared__ float EG[TS_ * 128];
    __shared__ float KK[TS_ * 128];
    __shared__ float QQ[TS_ * 128];
    __shared__ float VV[TS_ * 32];
    __shared__ float OT[TS_ * 32];
    __shared__ float BT[TS_];

    float S[16];
    #pragma unroll
    for (int j = 0; j < 16; ++j) S[j] = 0.0f;

    for (int t0 = 0; t0 < T_; t0 += TS_) {
        __syncthreads();
        // ---- stage 16 timesteps ----
        #pragma unroll
        for (int jj = 0; jj < 2; ++jj) {
            int f  = tid + 256 * jj;       // float4 index, 512 total
            int tt = f >> 5;
            int dk = (f & 31) * 4;
            size_t g = base + (size_t)(t0 + tt) * HID_ + dk;
            ((float4*)EG)[f] = *(const float4*)(eg + g);
            ((float4*)KK)[f] = *(const float4*)(kp + g);
            ((float4*)QQ)[f] = *(const float4*)(qp + g);
        }
        if (tid < 128) {
            int f  = tid;                  // 128 float4 = 16x32
            int tt = f >> 3;
            int vo = (f & 7) * 4;
            size_t g = base + (size_t)(t0 + tt) * HID_ + vc * 32 + vo;
            ((float4*)VV)[f] = *(const float4*)(vp + g);
        }
        if (tid < TS_) {
            size_t gi = ((size_t)b * T_ + t0 + tid) * H_ + h;
            BT[tid] = sigmoidf_(bbp[gi] + bsign * bdp[gi]);
        }
        __syncthreads();

        // ---- 16 sequential steps ----
        for (int tt = 0; tt < TS_; ++tt) {
            float egr[16], kkr[16], qqr[16];
            const float* Ep = EG + tt * 128 + kseg * 16;
            const float* Kp = KK + tt * 128 + kseg * 16;
            const float* Qp = QQ + tt * 128 + kseg * 16;
            #pragma unroll
            for (int j4 = 0; j4 < 4; ++j4) {
                *(float4*)&egr[j4 * 4] = *(const float4*)(Ep + j4 * 4);
                *(float4*)&kkr[j4 * 4] = *(const float4*)(Kp + j4 * 4);
                *(float4*)&qqr[j4 * 4] = *(const float4*)(Qp + j4 * 4);
            }
            float vcol = VV[tt * 32 + col];
            float btv  = BT[tt];

            float p = 0.0f;
            #pragma unroll
            for (int j = 0; j < 16; ++j) { S[j] *= egr[j]; p += kkr[j] * S[j]; }
            p += __shfl_xor(p, 1); p += __shfl_xor(p, 2); p += __shfl_xor(p, 4);

            float u = btv * (vcol - p);

            float oo = 0.0f;
            #pragma unroll
            for (int j = 0; j < 16; ++j) { S[j] += kkr[j] * u; oo += qqr[j] * S[j]; }
            oo += __shfl_xor(oo, 1); oo += __shfl_xor(oo, 2); oo += __shfl_xor(oo, 4);

            if (kseg == 0) OT[tt * 32 + col] = oo;
        }
        __syncthreads();

        // ---- write out 16x32 outputs, coalesced ----
        if (tid < 128) {
            int f  = tid;
            int tt = f >> 3;
            int vo = (f & 7) * 4;
            size_t g = base + (size_t)(t0 + tt) * HID_ + vc * 32 + vo;
            *(float4*)(op + g) = ((const float4*)OT)[f];
        }
    }
}

// ---------------------------------------------------------------------------
// o = lam*o_f + (1-lam)*o_s  -> per-head RMSNorm * onorm_w -> * sigmoid(gate)
// One block per (b,t). Writes result into `outp` (may alias `of`: each
// element's load precedes its own store; no cross-element address overlap).
// ---------------------------------------------------------------------------
__global__ __launch_bounds__(256) void mix_norm_gate_kernel(
    const float* of, const float* os, const float* lam_pre,
    const float* gate, const float* onorm_w, float* outp)
{
    const int bt  = blockIdx.x;
    const int tid = threadIdx.x;
    const size_t row = (size_t)bt * HID_;

    float val[8];
    #pragma unroll
    for (int jj = 0; jj < 8; ++jj) {
        int c = tid + 256 * jj;
        int h = c >> 7;
        float l = sigmoidf_(lam_pre[(size_t)bt * H_ + h]);
        val[jj] = l * of[row + c] + (1.0f - l) * os[row + c];
    }

    __shared__ float red[4][8];
    const int wv = tid >> 6;
    #pragma unroll
    for (int jj = 0; jj < 8; ++jj) {
        float v2 = val[jj] * val[jj];
        #pragma unroll
        for (int m = 1; m < 64; m <<= 1) v2 += __shfl_xor(v2, m);
        if ((tid & 63) == 0) red[wv][jj] = v2;
    }
    __syncthreads();
    const int wb = (tid >> 7) * 2;
    #pragma unroll
    for (int jj = 0; jj < 8; ++jj) {
        int c = tid + 256 * jj;
        float ss   = red[wb][jj] + red[wb + 1][jj];
        float mean = ss * (1.0f / 128.0f);
        float sc   = rsqrtf(mean + 1e-5f) * onorm_w[c & 127];
        float g    = sigmoidf_(gate[row + c]);
        outp[row + c] = val[jj] * sc * g;
    }
}

// ---------------------------------------------------------------------------
extern "C" void kernel_launch(void* const* d_in, const int* in_sizes, int n_in,
                              void* d_out, int out_size, void* d_ws, size_t ws_size,
                              hipStream_t stream) {
    const float* x       = (const float*)d_in[0];
    const float* Wq      = (const float*)d_in[1];
    const float* Wk      = (const float*)d_in[2];
    const float* Wv      = (const float*)d_in[3];
    const float* conv_wq = (const float*)d_in[4];
    const float* conv_wk = (const float*)d_in[5];
    const float* conv_wv = (const float*)d_in[6];
    const float* Wgb1    = (const float*)d_in[7];
    const float* Wgb2    = (const float*)d_in[8];
    const float* Wgd1    = (const float*)d_in[9];
    const float* Wgd2    = (const float*)d_in[10];
    const float* Wbb     = (const float*)d_in[11];
    const float* Wbd     = (const float*)d_in[12];
    const float* Wlam    = (const float*)d_in[13];
    const float* A_log   = (const float*)d_in[14];
    const float* dt_bias = (const float*)d_in[15];
    const float* Wg1     = (const float*)d_in[16];
    const float* Wg2     = (const float*)d_in[17];
    const float* bg2     = (const float*)d_in[18];
    const float* onorm_w = (const float*)d_in[19];
    const float* Wo      = (const float*)d_in[20];
    float* out = (float*)d_out;

    const size_t M = (size_t)B_ * T_;   // 2048

    float* ws = (float*)d_ws;
    size_t off = 0;
    auto alloc = [&](size_t n) { float* p = ws + off; off += n; return p; };
    float* bufQ = alloc(M * HID_);      // q (post conv+norm+scale)
    float* bufK = alloc(M * HID_);      // k (post conv+norm)
    float* bufV = alloc(M * HID_);      // v (post conv+silu)
    float* bufA = alloc(M * HID_);      // xq -> g_base -> exp(gf)
    float* bufB = alloc(M * HID_);      // xk -> g_delta -> exp(gs)
    float* bufC = alloc(M * HID_);      // xv -> o_f -> o_final
    float* bufD = alloc(M * HID_);      // o_s
    float* bufE = alloc(M * HID_);      // gate
    float* gbm  = alloc(M * DV_);       // x@Wgb1
    float* gdm  = alloc(M * DV_);       // x@Wgd1
    float* ggm  = alloc(M * DV_);       // x@Wg1
    float* bb   = alloc(M * H_);
    float* bd   = alloc(M * H_);
    float* lamp = alloc(M * H_);

    dim3 blk(256);
    auto gemm = [&](const float* A, const float* Bm, const float* bias, float* C,
                    int Mm, int Nn, int Kk) {
        dim3 grid((Nn + 63) / 64, (Mm + 63) / 64);
        sgemm_kernel<<<grid, blk, 0, stream>>>(A, Bm, bias, C, Mm, Nn, Kk);
    };

    // 1) QKV projections
    gemm(x, Wq, nullptr, bufA, (int)M, HID_, HID_);
    gemm(x, Wk, nullptr, bufB, (int)M, HID_, HID_);
    gemm(x, Wv, nullptr, bufC, (int)M, HID_, HID_);

    // 2) conv + silu (+ l2norm, q-scale)
    conv_silu_kernel<<<dim3(B_ * T_), blk, 0, stream>>>(bufA, conv_wq, bufQ, 2);
    conv_silu_kernel<<<dim3(B_ * T_), blk, 0, stream>>>(bufB, conv_wk, bufK, 1);
    conv_silu_kernel<<<dim3(B_ * T_), blk, 0, stream>>>(bufC, conv_wv, bufV, 0);

    // 3) low-rank projections + small heads
    gemm(x, Wgb1, nullptr, gbm, (int)M, DV_, HID_);
    gemm(x, Wgd1, nullptr, gdm, (int)M, DV_, HID_);
    gemm(x, Wg1,  nullptr, ggm, (int)M, DV_, HID_);
    gemm(x, Wbb,  nullptr, bb,  (int)M, H_, HID_);
    gemm(x, Wbd,  nullptr, bd,  (int)M, H_, HID_);
    gemm(x, Wlam, nullptr, lamp,(int)M, H_, HID_);

    // 4) expand low-rank
    gemm(gbm, Wgb2, nullptr, bufA, (int)M, HID_, DV_);
    gemm(gdm, Wgd2, nullptr, bufB, (int)M, HID_, DV_);
    gemm(ggm, Wg2,  bg2,     bufE, (int)M, HID_, DV_);

    // 5) decay gates -> exp(gf), exp(gs) in place
    decay_gate_kernel<<<dim3((unsigned)(M * HID_ / 256)), blk, 0, stream>>>(
        bufA, bufB, A_log, dt_bias);

    // 6) dual-state delta-rule recurrence
    fkda_kernel<<<dim3(256), blk, 0, stream>>>(bufQ, bufK, bufV, bufA, bufB,
                                               bb, bd, bufC, bufD);

    // 7) mix + rmsnorm + gate
    mix_norm_gate_kernel<<<dim3(B_ * T_), blk, 0, stream>>>(
        bufC, bufD, lamp, bufE, onorm_w, bufC);

    // 8) output projection
    gemm(bufC, Wo, nullptr, out, (int)M, HID_, HID_);
}

// Round 2
// 1174.995 us; speedup vs baseline: 2.2511x; 2.2511x over previous
//
#include <hip/hip_runtime.h>
#include <hip/hip_bf16.h>
#include <math.h>
#include <stdint.h>

#define B_   2
#define T_   1024
#define HID_ 2048
#define H_   16
#define DK_  128
#define DV_  128
#define TS_  16     // timesteps staged per LDS tile in recurrence

typedef __bf16 bf16;
typedef __attribute__((ext_vector_type(8))) __bf16 bf16x8;
typedef __attribute__((ext_vector_type(4))) float f32x4;

typedef __attribute__((address_space(3))) uint32_t* lds_ptr_t;
typedef const __attribute__((address_space(1))) uint32_t* glb_ptr_t;

__device__ __forceinline__ float sigmoidf_(float x) {
    return 1.0f / (1.0f + __expf(-x));
}

// async global->LDS, 16B per lane. lds base must be wave-uniform; HW scatters
// lane i to lds + i*16.
__device__ __forceinline__ void ldg_to_lds16(const bf16* g, bf16* lds) {
    __builtin_amdgcn_global_load_lds((glb_ptr_t)(uintptr_t)g,
                                     (lds_ptr_t)(uintptr_t)lds, 16, 0, 0);
}

// ---------------------------------------------------------------------------
// fp32 -> bf16 elementwise cast, 8 elems/thread
// ---------------------------------------------------------------------------
__global__ __launch_bounds__(256) void cast_bf16_kernel(
    const float* __restrict__ in, bf16* __restrict__ out)
{
    int i = blockIdx.x * 256 + threadIdx.x;
    float4 a = ((const float4*)in)[2 * i];
    float4 b = ((const float4*)in)[2 * i + 1];
    bf16x8 o;
    o[0] = (bf16)a.x; o[1] = (bf16)a.y; o[2] = (bf16)a.z; o[3] = (bf16)a.w;
    o[4] = (bf16)b.x; o[5] = (bf16)b.y; o[6] = (bf16)b.z; o[7] = (bf16)b.w;
    ((bf16x8*)out)[i] = o;
}

// ---------------------------------------------------------------------------
// W [K,N] fp32  ->  Wt [N,K] bf16 (transpose-cast). 32x32 tiles.
// grid (N/32, K/32), 256 threads.
// ---------------------------------------------------------------------------
__global__ __launch_bounds__(256) void tcast_kernel(
    const float* __restrict__ W, bf16* __restrict__ Wt, int K, int N)
{
    __shared__ float tile[32][33];
    const int k0 = blockIdx.y * 32, n0 = blockIdx.x * 32;
    const int r = threadIdx.x >> 5, c = threadIdx.x & 31;
    #pragma unroll
    for (int i = 0; i < 4; ++i)
        tile[r + 8 * i][c] = W[(size_t)(k0 + r + 8 * i) * N + n0 + c];
    __syncthreads();
    #pragma unroll
    for (int i = 0; i < 4; ++i)
        Wt[(size_t)(n0 + r + 8 * i) * K + k0 + c] = (bf16)tile[c][r + 8 * i];
}

// ---------------------------------------------------------------------------
// bf16 MFMA GEMM: C[M,N] = A[M,K] @ Bt[N,K]^T (+bias). 128x128 tile, BK=32,
// 256 threads (4 waves, 2x2 of 64x64 wave-tiles, 4x4 MFMA 16x16x32 each).
// global_load_lds width-16 staging, m97 2-barrier K-loop.
// Requires M%128==0, K%32==0, N%128==0.
// ---------------------------------------------------------------------------
__global__ __launch_bounds__(256) void mfma_gemm_kernel(
    const bf16* __restrict__ A, const bf16* __restrict__ Bt,
    const float* __restrict__ bias, void* __restrict__ Cout,
    int M, int N, int K, int bf16out)
{
    __shared__ bf16 As[128 * 32];   // As[row][k], 64B rows
    __shared__ bf16 Bs[128 * 32];   // Bs[n][k]

    const int tid  = threadIdx.x;
    const int w    = tid >> 6;
    const int lane = tid & 63;
    const int n0   = blockIdx.x * 128;
    const int m0   = blockIdx.y * 128;
    const int wm   = (w >> 1) * 64;
    const int wn   = (w & 1) * 64;

    const int lr = lane >> 2;          // staging row-in-16
    const int lc = (lane & 3) * 8;     // staging k-offset (bf16 elems)

    f32x4 acc[4][4];
    #pragma unroll
    for (int i = 0; i < 4; ++i)
        #pragma unroll
        for (int j = 0; j < 4; ++j) acc[i][j] = (f32x4)0.0f;

    const bf16* ApL = As + (wm + (lane & 15)) * 32 + (lane >> 4) * 8;
    const bf16* BpL = Bs + (wn + (lane & 15)) * 32 + (lane >> 4) * 8;

    for (int k0 = 0; k0 < K; k0 += 32) {
        #pragma unroll
        for (int i = 0; i < 2; ++i) {
            const int rr = (w * 2 + i) * 16 + lr;
            ldg_to_lds16(A  + (size_t)(m0 + rr) * K + k0 + lc, As + (w * 2 + i) * 512);
            ldg_to_lds16(Bt + (size_t)(n0 + rr) * K + k0 + lc, Bs + (w * 2 + i) * 512);
        }
        __syncthreads();   // drains vmcnt(0): staged data visible

        bf16x8 af[4], bfr[4];
        #pragma unroll
        for (int i = 0; i < 4; ++i) af[i]  = *(const bf16x8*)(ApL + i * 16 * 32);
        #pragma unroll
        for (int j = 0; j < 4; ++j) bfr[j] = *(const bf16x8*)(BpL + j * 16 * 32);
        #pragma unroll
        for (int i = 0; i < 4; ++i)
            #pragma unroll
            for (int j = 0; j < 4; ++j)
                acc[i][j] = __builtin_amdgcn_mfma_f32_16x16x32_bf16(
                    af[i], bfr[j], acc[i][j], 0, 0, 0);
        __syncthreads();   // all waves done reading before next overwrite
    }

    // epilogue: D col=lane&15, row=(lane>>4)*4+r
    #pragma unroll
    for (int i = 0; i < 4; ++i) {
        const int row = m0 + wm + i * 16 + (lane >> 4) * 4;
        #pragma unroll
        for (int j = 0; j < 4; ++j) {
            const int col = n0 + wn + j * 16 + (lane & 15);
            const float bv = bias ? bias[col] : 0.0f;
            #pragma unroll
            for (int r = 0; r < 4; ++r) {
                float v = acc[i][j][r] + bv;
                if (bf16out) ((bf16*)Cout)[(size_t)(row + r) * N + col] = (bf16)v;
                else         ((float*)Cout)[(size_t)(row + r) * N + col] = v;
            }
        }
    }
}

// ---------------------------------------------------------------------------
// Fused skinny GEMMs: bb/bd/lam = x @ {Wbb,Wbd,Wlam}  (N=16 each, K=2048).
// Block = 16 rows of x; 256 threads: (r=tid>>4, cg=tid&15), 3 cols/thread.
// ---------------------------------------------------------------------------
__global__ __launch_bounds__(256) void skinny3_kernel(
    const float* __restrict__ x, const float* __restrict__ Wbb,
    const float* __restrict__ Wbd, const float* __restrict__ Wlam,
    float* __restrict__ bb, float* __restrict__ bd, float* __restrict__ lam)
{
    __shared__ float xs[16][128];
    __shared__ float wsh[128][48];
    const int m0  = blockIdx.x * 16;
    const int tid = threadIdx.x;
    const int r = tid >> 4, cg = tid & 15;
    float acc0 = 0.f, acc1 = 0.f, acc2 = 0.f;

    for (int k0 = 0; k0 < HID_; k0 += 128) {
        __syncthreads();
        #pragma unroll
        for (int i = 0; i < 2; ++i) {
            int f = tid + 256 * i;
            int rr = f >> 5, cc = (f & 31) * 4;
            *(float4*)&xs[rr][cc] = *(const float4*)(x + (size_t)(m0 + rr) * HID_ + k0 + cc);
        }
        #pragma unroll
        for (int i = 0; i < 2; ++i) {
            int f = tid + 256 * i;
            int kk = f >> 2, cc = (f & 3) * 4;
            *(float4*)&wsh[kk][cc]      = *(const float4*)(Wbb  + (size_t)(k0 + kk) * 16 + cc);
            *(float4*)&wsh[kk][16 + cc] = *(const float4*)(Wbd  + (size_t)(k0 + kk) * 16 + cc);
            *(float4*)&wsh[kk][32 + cc] = *(const float4*)(Wlam + (size_t)(k0 + kk) * 16 + cc);
        }
        __syncthreads();
        #pragma unroll 8
        for (int kk = 0; kk < 128; ++kk) {
            float xv = xs[r][kk];
            acc0 += xv * wsh[kk][cg];
            acc1 += xv * wsh[kk][16 + cg];
            acc2 += xv * wsh[kk][32 + cg];
        }
    }
    size_t o = (size_t)(m0 + r) * 16 + cg;
    bb[o] = acc0; bd[o] = acc1; lam[o] = acc2;
}

// ---------------------------------------------------------------------------
// Causal depthwise conv1d (K=4) + SiLU, optional per-head l2norm (+q scale).
// mode: 0 = silu only (v); 1 = + l2norm (k); 2 = + l2norm * DK^-0.5 (q)
// ---------------------------------------------------------------------------
__global__ __launch_bounds__(256) void conv_silu_kernel(
    const float* __restrict__ xin, const float* __restrict__ w,
    float* __restrict__ yout, int mode)
{
    const int bt  = blockIdx.x;       // b*T + t
    const int t   = bt & (T_ - 1);
    const int tid = threadIdx.x;
    const size_t row = (size_t)bt * HID_;

    float val[8];
    #pragma unroll
    for (int jj = 0; jj < 8; ++jj) {
        int c = tid + 256 * jj;
        float4 wc = *(const float4*)(w + (size_t)c * 4);
        const float* xc = xin + row + c;
        float acc = wc.w * xc[0];
        if (t >= 1) acc += wc.z * xc[-HID_];
        if (t >= 2) acc += wc.y * xc[-2 * HID_];
        if (t >= 3) acc += wc.x * xc[-3 * HID_];
        val[jj] = acc * sigmoidf_(acc);
    }

    if (mode > 0) {
        __shared__ float red[4][8];
        const int wv = tid >> 6;
        #pragma unroll
        for (int jj = 0; jj < 8; ++jj) {
            float v2 = val[jj] * val[jj];
            #pragma unroll
            for (int m = 1; m < 64; m <<= 1) v2 += __shfl_xor(v2, m);
            if ((tid & 63) == 0) red[wv][jj] = v2;
        }
        __syncthreads();
        const int wb = (tid >> 7) * 2;
        #pragma unroll
        for (int jj = 0; jj < 8; ++jj) {
            float ss = red[wb][jj] + red[wb + 1][jj];
            float sc = rsqrtf(ss + 1e-6f);
            if (mode == 2) sc *= 0.08838834764831845f;     // DK^-0.5
            val[jj] *= sc;
        }
    }

    #pragma unroll
    for (int jj = 0; jj < 8; ++jj)
        yout[row + tid + 256 * jj] = val[jj];
}

// ---------------------------------------------------------------------------
// Decay gates: in-place  gb <- exp(gf), gd <- exp(gs)
// ---------------------------------------------------------------------------
__global__ __launch_bounds__(256) void decay_gate_kernel(
    float* gb, float* gd,
    const float* __restrict__ A_log, const float* __restrict__ dt_bias)
{
    size_t i = (size_t)blockIdx.x * 256 + threadIdx.x;
    int c = (int)(i & (HID_ - 1));
    int h = c >> 7;
    float a  = gb[i];
    float d  = gd[i];
    float na = -__expf(A_log[h]);
    float db = dt_bias[c];
    float xf = a + d + db;
    float xs = a - d + db;
    float spf = (xf > 20.0f) ? xf : log1pf(__expf(xf));
    float sps = (xs > 20.0f) ? xs : log1pf(__expf(xs));
    gb[i] = __expf(na * spf);
    gd[i] = __expf(na * sps);
}

// ---------------------------------------------------------------------------
// Dual-state gated delta-rule recurrence (unchanged from round 1).
// ---------------------------------------------------------------------------
__global__ __launch_bounds__(256) void fkda_kernel(
    const float* __restrict__ qp, const float* __restrict__ kp,
    const float* __restrict__ vp, const float* __restrict__ egf,
    const float* __restrict__ egs, const float* __restrict__ bbp,
    const float* __restrict__ bdp,
    float* __restrict__ ofp, float* __restrict__ osp)
{
    const int bx = blockIdx.x;
    const int vc = bx & 3;
    const int s  = (bx >> 2) & 1;
    const int h  = (bx >> 3) & 15;
    const int b  = bx >> 7;

    const float* eg = s ? egs : egf;
    float*       op = s ? osp : ofp;
    const float  bsign = s ? -1.0f : 1.0f;

    const int tid  = threadIdx.x;
    const int lane = tid & 63;
    const int wv   = tid >> 6;
    const int kseg = lane & 7;
    const int col  = wv * 8 + (lane >> 3);

    const size_t base = (size_t)b * T_ * HID_ + (size_t)h * DK_;

    __shared__ float EG[TS_ * 128];
    __shared__ float KK[TS_ * 128];
    __shared__ float QQ[TS_ * 128];
    __shared__ float VV[TS_ * 32];
    __shared__ float OT[TS_ * 32];
    __shared__ float BT[TS_];

    float S[16];
    #pragma unroll
    for (int j = 0; j < 16; ++j) S[j] = 0.0f;

    for (int t0 = 0; t0 < T_; t0 += TS_) {
        __syncthreads();
        #pragma unroll
        for (int jj = 0; jj < 2; ++jj) {
            int f  = tid + 256 * jj;
            int tt = f >> 5;
            int dk = (f & 31) * 4;
            size_t g = base + (size_t)(t0 + tt) * HID_ + dk;
            ((float4*)EG)[f] = *(const float4*)(eg + g);
            ((float4*)KK)[f] = *(const float4*)(kp + g);
            ((float4*)QQ)[f] = *(const float4*)(qp + g);
        }
        if (tid < 128) {
            int f  = tid;
            int tt = f >> 3;
            int vo = (f & 7) * 4;
            size_t g = base + (size_t)(t0 + tt) * HID_ + vc * 32 + vo;
            ((float4*)VV)[f] = *(const float4*)(vp + g);
        }
        if (tid < TS_) {
            size_t gi = ((size_t)b * T_ + t0 + tid) * H_ + h;
            BT[tid] = sigmoidf_(bbp[gi] + bsign * bdp[gi]);
        }
        __syncthreads();

        for (int tt = 0; tt < TS_; ++tt) {
            float egr[16], kkr[16], qqr[16];
            const float* Ep = EG + tt * 128 + kseg * 16;
            const float* Kp = KK + tt * 128 + kseg * 16;
            const float* Qp = QQ + tt * 128 + kseg * 16;
            #pragma unroll
            for (int j4 = 0; j4 < 4; ++j4) {
                *(float4*)&egr[j4 * 4] = *(const float4*)(Ep + j4 * 4);
                *(float4*)&kkr[j4 * 4] = *(const float4*)(Kp + j4 * 4);
                *(float4*)&qqr[j4 * 4] = *(const float4*)(Qp + j4 * 4);
            }
            float vcol = VV[tt * 32 + col];
            float btv  = BT[tt];

            float p = 0.0f;
            #pragma unroll
            for (int j = 0; j < 16; ++j) { S[j] *= egr[j]; p += kkr[j] * S[j]; }
            p += __shfl_xor(p, 1); p += __shfl_xor(p, 2); p += __shfl_xor(p, 4);

            float u = btv * (vcol - p);

            float oo = 0.0f;
            #pragma unroll
            for (int j = 0; j < 16; ++j) { S[j] += kkr[j] * u; oo += qqr[j] * S[j]; }
            oo += __shfl_xor(oo, 1); oo += __shfl_xor(oo, 2); oo += __shfl_xor(oo, 4);

            if (kseg == 0) OT[tt * 32 + col] = oo;
        }
        __syncthreads();

        if (tid < 128) {
            int f  = tid;
            int tt = f >> 3;
            int vo = (f & 7) * 4;
            size_t g = base + (size_t)(t0 + tt) * HID_ + vc * 32 + vo;
            *(float4*)(op + g) = ((const float4*)OT)[f];
        }
    }
}

// ---------------------------------------------------------------------------
// o = lam*o_f + (1-lam)*o_s -> per-head RMSNorm * onorm_w -> * sigmoid(gate)
// Writes bf16 (feeds the Wo MFMA GEMM).
// ---------------------------------------------------------------------------
__global__ __launch_bounds__(256) void mix_norm_gate_kernel(
    const float* of, const float* os, const float* lam_pre,
    const float* gate, const float* onorm_w, bf16* outp)
{
    const int bt  = blockIdx.x;
    const int tid = threadIdx.x;
    const size_t row = (size_t)bt * HID_;

    float val[8];
    #pragma unroll
    for (int jj = 0; jj < 8; ++jj) {
        int c = tid + 256 * jj;
        int h = c >> 7;
        float l = sigmoidf_(lam_pre[(size_t)bt * H_ + h]);
        val[jj] = l * of[row + c] + (1.0f - l) * os[row + c];
    }

    __shared__ float red[4][8];
    const int wv = tid >> 6;
    #pragma unroll
    for (int jj = 0; jj < 8; ++jj) {
        float v2 = val[jj] * val[jj];
        #pragma unroll
        for (int m = 1; m < 64; m <<= 1) v2 += __shfl_xor(v2, m);
        if ((tid & 63) == 0) red[wv][jj] = v2;
    }
    __syncthreads();
    const int wb = (tid >> 7) * 2;
    #pragma unroll
    for (int jj = 0; jj < 8; ++jj) {
        int c = tid + 256 * jj;
        float ss   = red[wb][jj] + red[wb + 1][jj];
        float mean = ss * (1.0f / 128.0f);
        float sc   = rsqrtf(mean + 1e-5f) * onorm_w[c & 127];
        float g    = sigmoidf_(gate[row + c]);
        outp[row + c] = (bf16)(val[jj] * sc * g);
    }
}

// ---------------------------------------------------------------------------
extern "C" void kernel_launch(void* const* d_in, const int* in_sizes, int n_in,
                              void* d_out, int out_size, void* d_ws, size_t ws_size,
                              hipStream_t stream) {
    const float* x       = (const float*)d_in[0];
    const float* Wq      = (const float*)d_in[1];
    const float* Wk      = (const float*)d_in[2];
    const float* Wv      = (const float*)d_in[3];
    const float* conv_wq = (const float*)d_in[4];
    const float* conv_wk = (const float*)d_in[5];
    const float* conv_wv = (const float*)d_in[6];
    const float* Wgb1    = (const float*)d_in[7];
    const float* Wgb2    = (const float*)d_in[8];
    const float* Wgd1    = (const float*)d_in[9];
    const float* Wgd2    = (const float*)d_in[10];
    const float* Wbb     = (const float*)d_in[11];
    const float* Wbd     = (const float*)d_in[12];
    const float* Wlam    = (const float*)d_in[13];
    const float* A_log   = (const float*)d_in[14];
    const float* dt_bias = (const float*)d_in[15];
    const float* Wg1     = (const float*)d_in[16];
    const float* Wg2     = (const float*)d_in[17];
    const float* bg2     = (const float*)d_in[18];
    const float* onorm_w = (const float*)d_in[19];
    const float* Wo      = (const float*)d_in[20];
    float* out = (float*)d_out;

    const size_t M = (size_t)B_ * T_;   // 2048

    float* ws = (float*)d_ws;
    size_t off = 0;
    auto alloc = [&](size_t n) { float* p = ws + off; off += n; return p; };
    float* bufQ = alloc(M * HID_);
    float* bufK = alloc(M * HID_);
    float* bufV = alloc(M * HID_);
    float* bufA = alloc(M * HID_);      // xq-pre -> exp(gf)
    float* bufB = alloc(M * HID_);      // xk-pre -> exp(gs)
    float* bufC = alloc(M * HID_);      // xv-pre -> o_f
    float* bufD = alloc(M * HID_);      // o_s
    float* bufE = alloc(M * HID_);      // gate
    float* bb   = alloc(M * H_);
    float* bd   = alloc(M * H_);
    float* lamp = alloc(M * H_);
    bf16* xb    = (bf16*)alloc(M * HID_ / 2);        // x, bf16
    bf16* obf   = (bf16*)alloc(M * HID_ / 2);        // mix output, bf16
    bf16* wbig  = (bf16*)alloc((size_t)HID_ * HID_ / 2);  // reused big-W^T bf16
    bf16* wmid  = (bf16*)alloc((size_t)HID_ * DV_ / 2);   // W*1^T  [128,2048]
    bf16* wexp  = (bf16*)alloc((size_t)HID_ * DV_ / 2);   // W*2^T  [2048,128]
    bf16* gbm   = (bf16*)alloc(M * DV_ / 2);
    bf16* gdm   = (bf16*)alloc(M * DV_ / 2);
    bf16* ggm   = (bf16*)alloc(M * DV_ / 2);

    dim3 blk(256);
    auto gemm = [&](const bf16* A, const bf16* Bt, const float* bias, void* C,
                    int Mm, int Nn, int Kk, int bf16out) {
        dim3 grid(Nn / 128, Mm / 128);
        mfma_gemm_kernel<<<grid, blk, 0, stream>>>(A, Bt, bias, C, Mm, Nn, Kk, bf16out);
    };
    auto tcast = [&](const float* W, bf16* Wt, int Kk, int Nn) {
        tcast_kernel<<<dim3(Nn / 32, Kk / 32), blk, 0, stream>>>(W, Wt, Kk, Nn);
    };

    // 0) cast x to bf16
    cast_bf16_kernel<<<dim3((unsigned)(M * HID_ / 8 / 256)), blk, 0, stream>>>(x, xb);

    // 1) QKV projections (bf16 MFMA), weights transpose-cast on the fly
    tcast(Wq, wbig, HID_, HID_);  gemm(xb, wbig, nullptr, bufA, (int)M, HID_, HID_, 0);
    tcast(Wk, wbig, HID_, HID_);  gemm(xb, wbig, nullptr, bufB, (int)M, HID_, HID_, 0);
    tcast(Wv, wbig, HID_, HID_);  gemm(xb, wbig, nullptr, bufC, (int)M, HID_, HID_, 0);

    // 2) conv + silu (+ l2norm, q-scale)
    conv_silu_kernel<<<dim3(B_ * T_), blk, 0, stream>>>(bufA, conv_wq, bufQ, 2);
    conv_silu_kernel<<<dim3(B_ * T_), blk, 0, stream>>>(bufB, conv_wk, bufK, 1);
    conv_silu_kernel<<<dim3(B_ * T_), blk, 0, stream>>>(bufC, conv_wv, bufV, 0);

    // 3) skinny heads bb/bd/lam (fp32, fused)
    skinny3_kernel<<<dim3((unsigned)(M / 16)), blk, 0, stream>>>(
        x, Wbb, Wbd, Wlam, bb, bd, lamp);

    // 4) low-rank mid GEMMs (N=128, bf16 out) then expand (K=128, fp32 out)
    tcast(Wgb1, wmid, HID_, DV_);  gemm(xb, wmid, nullptr, gbm, (int)M, DV_, HID_, 1);
    tcast(Wgd1, wmid, HID_, DV_);  gemm(xb, wmid, nullptr, gdm, (int)M, DV_, HID_, 1);
    tcast(Wg1,  wmid, HID_, DV_);  gemm(xb, wmid, nullptr, ggm, (int)M, DV_, HID_, 1);

    tcast(Wgb2, wexp, DV_, HID_);  gemm(gbm, wexp, nullptr, bufA, (int)M, HID_, DV_, 0);
    tcast(Wgd2, wexp, DV_, HID_);  gemm(gdm, wexp, nullptr, bufB, (int)M, HID_, DV_, 0);
    tcast(Wg2,  wexp, DV_, HID_);  gemm(ggm, wexp, bg2,     bufE, (int)M, HID_, DV_, 0);

    // 5) decay gates -> exp(gf), exp(gs) in place
    decay_gate_kernel<<<dim3((unsigned)(M * HID_ / 256)), blk, 0, stream>>>(
        bufA, bufB, A_log, dt_bias);

    // 6) dual-state delta-rule recurrence
    fkda_kernel<<<dim3(256), blk, 0, stream>>>(bufQ, bufK, bufV, bufA, bufB,
                                               bb, bd, bufC, bufD);

    // 7) mix + rmsnorm + gate -> bf16
    mix_norm_gate_kernel<<<dim3(B_ * T_), blk, 0, stream>>>(
        bufC, bufD, lamp, bufE, onorm_w, obf);

    // 8) output projection (bf16 MFMA)
    tcast(Wo, wbig, HID_, HID_);
    gemm(obf, wbig, nullptr, out, (int)M, HID_, HID_, 0);
}

// Round 3
// 959.587 us; speedup vs baseline: 2.7564x; 1.2245x over previous
//
#include <hip/hip_runtime.h>
#include <hip/hip_bf16.h>
#include <math.h>
#include <stdint.h>

#define B_   2
#define T_   1024
#define HID_ 2048
#define H_   16
#define DK_  128
#define DV_  128
#define TS_  16     // timesteps staged per LDS tile in recurrence

typedef __bf16 bf16;
typedef __attribute__((ext_vector_type(8))) __bf16 bf16x8;
typedef __attribute__((ext_vector_type(4))) float f32x4;

typedef __attribute__((address_space(3))) uint32_t* lds_ptr_t;
typedef const __attribute__((address_space(1))) uint32_t* glb_ptr_t;

__device__ __forceinline__ float sigmoidf_(float x) {
    return 1.0f / (1.0f + __expf(-x));
}

// async global->LDS, 16B per lane. LDS base wave-uniform (HW: lane i ->
// base + 16*i); global address is per-lane.
__device__ __forceinline__ void ldg_to_lds16(const void* g, void* lds) {
    __builtin_amdgcn_global_load_lds((glb_ptr_t)(uintptr_t)g,
                                     (lds_ptr_t)(uintptr_t)lds, 16, 0, 0);
}

// ---------------------------------------------------------------------------
// fp32 -> bf16 elementwise cast, 8 elems/thread
// ---------------------------------------------------------------------------
__global__ __launch_bounds__(256) void cast_bf16_kernel(
    const float* __restrict__ in, bf16* __restrict__ out)
{
    int i = blockIdx.x * 256 + threadIdx.x;
    float4 a = ((const float4*)in)[2 * i];
    float4 b = ((const float4*)in)[2 * i + 1];
    bf16x8 o;
    o[0] = (bf16)a.x; o[1] = (bf16)a.y; o[2] = (bf16)a.z; o[3] = (bf16)a.w;
    o[4] = (bf16)b.x; o[5] = (bf16)b.y; o[6] = (bf16)b.z; o[7] = (bf16)b.w;
    ((bf16x8*)out)[i] = o;
}

// ---------------------------------------------------------------------------
// W [K,N] fp32  ->  Wt [N,K] bf16 (transpose-cast). 32x32 tiles.
// ---------------------------------------------------------------------------
__global__ __launch_bounds__(256) void tcast_kernel(
    const float* __restrict__ W, bf16* __restrict__ Wt, int K, int N)
{
    __shared__ float tile[32][33];
    const int k0 = blockIdx.y * 32, n0 = blockIdx.x * 32;
    const int r = threadIdx.x >> 5, c = threadIdx.x & 31;
    #pragma unroll
    for (int i = 0; i < 4; ++i)
        tile[r + 8 * i][c] = W[(size_t)(k0 + r + 8 * i) * N + n0 + c];
    __syncthreads();
    #pragma unroll
    for (int i = 0; i < 4; ++i)
        Wt[(size_t)(n0 + r + 8 * i) * K + k0 + c] = (bf16)tile[c][r + 8 * i];
}

// ---------------------------------------------------------------------------
// bf16 MFMA GEMM: C[M,N] = A[M,K] @ Bt[N,K]^T (+bias). 128x128 tile, BK=32.
// lda/ldc = element row strides of A/C; Bt row stride = Kfull.
// ksplit>0: blockIdx.z handles K-range [z*ksplit, (z+1)*ksplit), writes to
// plane Cout + z*M*N (fp32).
// ---------------------------------------------------------------------------
__global__ __launch_bounds__(256) void mfma_gemm_kernel(
    const bf16* __restrict__ A, const bf16* __restrict__ Bt,
    const float* __restrict__ bias, void* __restrict__ Cout,
    int M, int N, int Kfull, int lda, int ldc, int ksplit, int bf16out)
{
    __shared__ bf16 As[128 * 32];
    __shared__ bf16 Bs[128 * 32];

    const int tid  = threadIdx.x;
    const int w    = tid >> 6;
    const int lane = tid & 63;
    const int n0   = blockIdx.x * 128;
    const int m0   = blockIdx.y * 128;
    const int wm   = (w >> 1) * 64;
    const int wn   = (w & 1) * 64;

    int kbeg = 0, kend = Kfull;
    float* Cf = (float*)Cout;
    if (ksplit > 0) {
        kbeg = blockIdx.z * ksplit;
        kend = kbeg + ksplit;
        Cf  += (size_t)blockIdx.z * M * N;
    }

    const int lr = lane >> 2;
    const int lc = (lane & 3) * 8;

    f32x4 acc[4][4];
    #pragma unroll
    for (int i = 0; i < 4; ++i)
        #pragma unroll
        for (int j = 0; j < 4; ++j) acc[i][j] = (f32x4)0.0f;

    const bf16* ApL = As + (wm + (lane & 15)) * 32 + (lane >> 4) * 8;
    const bf16* BpL = Bs + (wn + (lane & 15)) * 32 + (lane >> 4) * 8;

    for (int k0 = kbeg; k0 < kend; k0 += 32) {
        #pragma unroll
        for (int i = 0; i < 2; ++i) {
            const int rr = (w * 2 + i) * 16 + lr;
            ldg_to_lds16(A  + (size_t)(m0 + rr) * lda   + k0 + lc, As + (w * 2 + i) * 512);
            ldg_to_lds16(Bt + (size_t)(n0 + rr) * Kfull + k0 + lc, Bs + (w * 2 + i) * 512);
        }
        __syncthreads();

        bf16x8 af[4], bfr[4];
        #pragma unroll
        for (int i = 0; i < 4; ++i) af[i]  = *(const bf16x8*)(ApL + i * 16 * 32);
        #pragma unroll
        for (int j = 0; j < 4; ++j) bfr[j] = *(const bf16x8*)(BpL + j * 16 * 32);
        #pragma unroll
        for (int i = 0; i < 4; ++i)
            #pragma unroll
            for (int j = 0; j < 4; ++j)
                acc[i][j] = __builtin_amdgcn_mfma_f32_16x16x32_bf16(
                    af[i], bfr[j], acc[i][j], 0, 0, 0);
        __syncthreads();
    }

    #pragma unroll
    for (int i = 0; i < 4; ++i) {
        const int row = m0 + wm + i * 16 + (lane >> 4) * 4;
        #pragma unroll
        for (int j = 0; j < 4; ++j) {
            const int col = n0 + wn + j * 16 + (lane & 15);
            const float bv = bias ? bias[col] : 0.0f;
            #pragma unroll
            for (int r = 0; r < 4; ++r) {
                float v = acc[i][j][r] + bv;
                if (bf16out) ((bf16*)Cout)[(size_t)(row + r) * ldc + col] = (bf16)v;
                else         Cf[(size_t)(row + r) * ldc + col] = v;
            }
        }
    }
}

// ---------------------------------------------------------------------------
// Sum 4 split-K fp32 planes [M,384] -> bf16
// ---------------------------------------------------------------------------
__global__ __launch_bounds__(256) void mid_reduce_kernel(
    const float* __restrict__ midp, bf16* __restrict__ midb)
{
    const size_t plane = (size_t)2048 * 384 / 4;   // float4s per plane
    size_t i = (size_t)blockIdx.x * 256 + threadIdx.x;
    float4 a = ((const float4*)midp)[i];
    float4 b = ((const float4*)midp)[i + plane];
    float4 c = ((const float4*)midp)[i + 2 * plane];
    float4 d = ((const float4*)midp)[i + 3 * plane];
    float4 s;
    s.x = a.x + b.x + c.x + d.x; s.y = a.y + b.y + c.y + d.y;
    s.z = a.z + b.z + c.z + d.z; s.w = a.w + b.w + c.w + d.w;
    bf16 o[4] = {(bf16)s.x, (bf16)s.y, (bf16)s.z, (bf16)s.w};
    *(uint64_t*)(midb + 4 * i) = *(uint64_t*)o;
}

// ---------------------------------------------------------------------------
// Fused skinny GEMMs: bb/bd/lam = x @ {Wbb,Wbd,Wlam}  (N=16 each, K=2048).
// ---------------------------------------------------------------------------
__global__ __launch_bounds__(256) void skinny3_kernel(
    const float* __restrict__ x, const float* __restrict__ Wbb,
    const float* __restrict__ Wbd, const float* __restrict__ Wlam,
    float* __restrict__ bb, float* __restrict__ bd, float* __restrict__ lam)
{
    __shared__ float xs[16][128];
    __shared__ float wsh[128][48];
    const int m0  = blockIdx.x * 16;
    const int tid = threadIdx.x;
    const int r = tid >> 4, cg = tid & 15;
    float acc0 = 0.f, acc1 = 0.f, acc2 = 0.f;

    for (int k0 = 0; k0 < HID_; k0 += 128) {
        __syncthreads();
        #pragma unroll
        for (int i = 0; i < 2; ++i) {
            int f = tid + 256 * i;
            int rr = f >> 5, cc = (f & 31) * 4;
            *(float4*)&xs[rr][cc] = *(const float4*)(x + (size_t)(m0 + rr) * HID_ + k0 + cc);
        }
        #pragma unroll
        for (int i = 0; i < 2; ++i) {
            int f = tid + 256 * i;
            int kk = f >> 2, cc = (f & 3) * 4;
            *(float4*)&wsh[kk][cc]      = *(const float4*)(Wbb  + (size_t)(k0 + kk) * 16 + cc);
            *(float4*)&wsh[kk][16 + cc] = *(const float4*)(Wbd  + (size_t)(k0 + kk) * 16 + cc);
            *(float4*)&wsh[kk][32 + cc] = *(const float4*)(Wlam + (size_t)(k0 + kk) * 16 + cc);
        }
        __syncthreads();
        #pragma unroll 8
        for (int kk = 0; kk < 128; ++kk) {
            float xv = xs[r][kk];
            acc0 += xv * wsh[kk][cg];
            acc1 += xv * wsh[kk][16 + cg];
            acc2 += xv * wsh[kk][32 + cg];
        }
    }
    size_t o = (size_t)(m0 + r) * 16 + cg;
    bb[o] = acc0; bd[o] = acc1; lam[o] = acc2;
}

// ---------------------------------------------------------------------------
// Causal depthwise conv1d (K=4) + SiLU, + optional per-head l2norm.
// Reads strided slice of fused QKV pre-activations (row stride ldx, col off).
// mode: 0 = silu only -> fp32 out (v); 1 = + l2norm -> bf16 (k);
//       2 = + l2norm * DK^-0.5 -> bf16 (q)
// ---------------------------------------------------------------------------
__global__ __launch_bounds__(256) void conv_silu_kernel(
    const float* __restrict__ xin, int ldx, int coloff,
    const float* __restrict__ w,
    bf16* __restrict__ ybf, float* __restrict__ yf32, int mode)
{
    const int bt  = blockIdx.x;
    const int t   = bt & (T_ - 1);
    const int tid = threadIdx.x;
    const float* xr = xin + (size_t)bt * ldx + coloff;

    float val[8];
    #pragma unroll
    for (int jj = 0; jj < 8; ++jj) {
        int c = tid + 256 * jj;
        float4 wc = *(const float4*)(w + (size_t)c * 4);
        const float* xc = xr + c;
        float acc = wc.w * xc[0];
        if (t >= 1) acc += wc.z * xc[-ldx];
        if (t >= 2) acc += wc.y * xc[-2 * ldx];
        if (t >= 3) acc += wc.x * xc[-3 * ldx];
        val[jj] = acc * sigmoidf_(acc);
    }

    if (mode > 0) {
        __shared__ float red[4][8];
        const int wv = tid >> 6;
        #pragma unroll
        for (int jj = 0; jj < 8; ++jj) {
            float v2 = val[jj] * val[jj];
            #pragma unroll
            for (int m = 1; m < 64; m <<= 1) v2 += __shfl_xor(v2, m);
            if ((tid & 63) == 0) red[wv][jj] = v2;
        }
        __syncthreads();
        const int wb = (tid >> 7) * 2;
        #pragma unroll
        for (int jj = 0; jj < 8; ++jj) {
            float ss = red[wb][jj] + red[wb + 1][jj];
            float sc = rsqrtf(ss + 1e-6f);
            if (mode == 2) sc *= 0.08838834764831845f;     // DK^-0.5
            val[jj] *= sc;
        }
    }

    const size_t row = (size_t)bt * HID_;
    if (mode == 0) {
        #pragma unroll
        for (int jj = 0; jj < 8; ++jj)
            yf32[row + tid + 256 * jj] = val[jj];
    } else {
        #pragma unroll
        for (int jj = 0; jj < 8; ++jj)
            ybf[row + tid + 256 * jj] = (bf16)val[jj];
    }
}

// ---------------------------------------------------------------------------
// Decay gates: in-place  gb <- exp(gf), gd <- exp(gs)   (fp32 throughout)
// ---------------------------------------------------------------------------
__global__ __launch_bounds__(256) void decay_gate_kernel(
    float* gb, float* gd,
    const float* __restrict__ A_log, const float* __restrict__ dt_bias)
{
    size_t i = (size_t)blockIdx.x * 256 + threadIdx.x;
    int c = (int)(i & (HID_ - 1));
    int h = c >> 7;
    float a  = gb[i];
    float d  = gd[i];
    float na = -__expf(A_log[h]);
    float db = dt_bias[c];
    float xf = a + d + db;
    float xs = a - d + db;
    float spf = (xf > 20.0f) ? xf : log1pf(__expf(xf));
    float sps = (xs > 20.0f) ? xs : log1pf(__expf(xs));
    gb[i] = __expf(na * spf);
    gd[i] = __expf(na * sps);
}

// ---------------------------------------------------------------------------
// Dual-state gated delta-rule recurrence, v2.
// Grid: 512 blocks: bx = sv*32 + bh;  bh = b*16+h (0..31), sv = s*8+vc.
// (same-%8 bx share (b,h) -> same XCD for q/k L2 reuse.)
// Block: 256 threads = 4 waves; wave = 4 cols x 16 ksegs (8 k's each).
// S[8] fp32 per thread. q/k staged bf16, eg fp32, via global_load_lds.
// ---------------------------------------------------------------------------
__global__ __launch_bounds__(256) void fkda_kernel(
    const bf16* __restrict__ qp, const bf16* __restrict__ kp,
    const float* __restrict__ vp, const float* __restrict__ egf,
    const float* __restrict__ egs, const float* __restrict__ bbp,
    const float* __restrict__ bdp,
    float* __restrict__ ofp, float* __restrict__ osp)
{
    const int bx = blockIdx.x;
    const int bh = bx & 31;
    const int sv = bx >> 5;
    const int b  = bh >> 4;
    const int h  = bh & 15;
    const int s  = sv >> 3;
    const int vc = sv & 7;

    const float* eg = s ? egs : egf;
    float*       op = s ? osp : ofp;
    const float  bsign = s ? -1.0f : 1.0f;

    const int tid  = threadIdx.x;
    const int lane = tid & 63;
    const int w    = tid >> 6;
    const int kseg = lane & 15;             // 8 k's each: kseg*8
    const int colb = w * 4 + (lane >> 4);   // 0..15 within block

    const size_t base = (size_t)b * T_ * HID_ + (size_t)h * DK_;  // + t*HID_

    __shared__ float EG[TS_ * 128];     // 8 KB
    __shared__ bf16  KK[TS_ * 128];     // 4 KB
    __shared__ bf16  QQ[TS_ * 128];     // 4 KB
    __shared__ float VV[TS_ * 16];      // 1 KB
    __shared__ float OT[TS_ * 16];      // 1 KB
    __shared__ float BT[TS_];

    float S[8];
    #pragma unroll
    for (int j = 0; j < 8; ++j) S[j] = 0.0f;

    for (int t0 = 0; t0 < T_; t0 += TS_) {
        // ---- stage tile ----
        // EG fp32: 8 wave-instrs (2 per wave): instr n covers f=n*64+lane,
        // tt=f>>5, col=(f&31)*4
        #pragma unroll
        for (int i = 0; i < 2; ++i) {
            int n = w * 2 + i;
            int f = n * 64 + lane;
            int tt = f >> 5, co = (f & 31) * 4;
            ldg_to_lds16(eg + base + (size_t)(t0 + tt) * HID_ + co, EG + n * 256);
        }
        // K/Q bf16: 4 wave-instrs each (1 per wave): f=w*64+lane, tt=f>>4,
        // col=(f&15)*8
        {
            int f = w * 64 + lane;
            int tt = f >> 4, co = (f & 15) * 8;
            size_t g = base + (size_t)(t0 + tt) * HID_ + co;
            ldg_to_lds16(kp + g, KK + w * 512);
            ldg_to_lds16(qp + g, QQ + w * 512);
        }
        if (tid < 64) {       // V: 16t x 16cols fp32
            int tt = tid >> 2, vo = (tid & 3) * 4;
            size_t g = base + (size_t)(t0 + tt) * HID_ + vc * 16 + vo;
            ((float4*)VV)[tid] = *(const float4*)(vp + g);
        }
        if (tid < TS_) {
            size_t gi = ((size_t)b * T_ + t0 + tid) * H_ + h;
            BT[tid] = sigmoidf_(bbp[gi] + bsign * bdp[gi]);
        }
        __syncthreads();

        // ---- 16 sequential steps ----
        for (int tt = 0; tt < TS_; ++tt) {
            float e[8];
            *(float4*)&e[0] = *(const float4*)(EG + tt * 128 + kseg * 8);
            *(float4*)&e[4] = *(const float4*)(EG + tt * 128 + kseg * 8 + 4);
            bf16x8 k8 = *(const bf16x8*)(KK + tt * 128 + kseg * 8);
            bf16x8 q8 = *(const bf16x8*)(QQ + tt * 128 + kseg * 8);
            float vcol = VV[tt * 16 + colb];
            float btv  = BT[tt];

            float kf[8];
            #pragma unroll
            for (int j = 0; j < 8; ++j) kf[j] = (float)k8[j];

            float p = 0.0f;
            #pragma unroll
            for (int j = 0; j < 8; ++j) { S[j] *= e[j]; p += kf[j] * S[j]; }
            p += __shfl_xor(p, 1); p += __shfl_xor(p, 2);
            p += __shfl_xor(p, 4); p += __shfl_xor(p, 8);

            float u = btv * (vcol - p);

            float oo = 0.0f;
            #pragma unroll
            for (int j = 0; j < 8; ++j) { S[j] += kf[j] * u; oo += (float)q8[j] * S[j]; }
            oo += __shfl_xor(oo, 1); oo += __shfl_xor(oo, 2);
            oo += __shfl_xor(oo, 4); oo += __shfl_xor(oo, 8);

            if ((lane & 15) == 0) OT[tt * 16 + colb] = oo;
        }
        __syncthreads();

        // ---- flush 16x16 outputs ----
        if (tid < 64) {
            int tt = tid >> 2, vo = (tid & 3) * 4;
            size_t g = base + (size_t)(t0 + tt) * HID_ + vc * 16 + vo;
            *(float4*)(op + g) = ((const float4*)OT)[tid];
        }
        // next-iter staging writes EG/KK/QQ/VV (disjoint from OT);
        // post-stage __syncthreads covers the OT flush reads.
    }
}

// ---------------------------------------------------------------------------
// o = lam*o_f + (1-lam)*o_s -> per-head RMSNorm * onorm_w -> * sigmoid(gate)
// ---------------------------------------------------------------------------
__global__ __launch_bounds__(256) void mix_norm_gate_kernel(
    const float* of, const float* os, const float* lam_pre,
    const float* gate, const float* onorm_w, bf16* outp)
{
    const int bt  = blockIdx.x;
    const int tid = threadIdx.x;
    const size_t row = (size_t)bt * HID_;

    float val[8];
    #pragma unroll
    for (int jj = 0; jj < 8; ++jj) {
        int c = tid + 256 * jj;
        int h = c >> 7;
        float l = sigmoidf_(lam_pre[(size_t)bt * H_ + h]);
        val[jj] = l * of[row + c] + (1.0f - l) * os[row + c];
    }

    __shared__ float red[4][8];
    const int wv = tid >> 6;
    #pragma unroll
    for (int jj = 0; jj < 8; ++jj) {
        float v2 = val[jj] * val[jj];
        #pragma unroll
        for (int m = 1; m < 64; m <<= 1) v2 += __shfl_xor(v2, m);
        if ((tid & 63) == 0) red[wv][jj] = v2;
    }
    __syncthreads();
    const int wb = (tid >> 7) * 2;
    #pragma unroll
    for (int jj = 0; jj < 8; ++jj) {
        int c = tid + 256 * jj;
        float ss   = red[wb][jj] + red[wb + 1][jj];
        float mean = ss * (1.0f / 128.0f);
        float sc   = rsqrtf(mean + 1e-5f) * onorm_w[c & 127];
        float g    = sigmoidf_(gate[row + c]);
        outp[row + c] = (bf16)(val[jj] * sc * g);
    }
}

// ---------------------------------------------------------------------------
extern "C" void kernel_launch(void* const* d_in, const int* in_sizes, int n_in,
                              void* d_out, int out_size, void* d_ws, size_t ws_size,
                              hipStream_t stream) {
    const float* x       = (const float*)d_in[0];
    const float* Wq      = (const float*)d_in[1];
    const float* Wk      = (const float*)d_in[2];
    const float* Wv      = (const float*)d_in[3];
    const float* conv_wq = (const float*)d_in[4];
    const float* conv_wk = (const float*)d_in[5];
    const float* conv_wv = (const float*)d_in[6];
    const float* Wgb1    = (const float*)d_in[7];
    const float* Wgb2    = (const float*)d_in[8];
    const float* Wgd1    = (const float*)d_in[9];
    const float* Wgd2    = (const float*)d_in[10];
    const float* Wbb     = (const float*)d_in[11];
    const float* Wbd     = (const float*)d_in[12];
    const float* Wlam    = (const float*)d_in[13];
    const float* A_log   = (const float*)d_in[14];
    const float* dt_bias = (const float*)d_in[15];
    const float* Wg1     = (const float*)d_in[16];
    const float* Wg2     = (const float*)d_in[17];
    const float* bg2     = (const float*)d_in[18];
    const float* onorm_w = (const float*)d_in[19];
    const float* Wo      = (const float*)d_in[20];
    float* out = (float*)d_out;

    const size_t M = (size_t)B_ * T_;   // 2048

    float* ws = (float*)d_ws;
    size_t off = 0;
    auto alloc = [&](size_t nfloats) { float* p = ws + off; off += nfloats; return p; };

    float* bufQKV = alloc(M * 3 * HID_);          // QKV preacts; later midp+midb
    float* wqkvTf = alloc(M * 3 * HID_ / 2);      // [6144,2048] bf16; later wmid/wexp/wo
    float* xbf    = alloc(M * HID_ / 2);
    float* bufQf  = alloc(M * HID_ / 2);          // q bf16
    float* bufKf  = alloc(M * HID_ / 2);          // k bf16
    float* bufV   = alloc(M * HID_);
    float* bufA   = alloc(M * HID_);              // g_base -> exp(gf)
    float* bufB   = alloc(M * HID_);              // g_delta -> exp(gs)
    float* bufC   = alloc(M * HID_);              // o_f
    float* bufD   = alloc(M * HID_);              // o_s
    float* bufE   = alloc(M * HID_);              // gate
    float* obff   = alloc(M * HID_ / 2);
    float* bb     = alloc(M * H_);
    float* bd     = alloc(M * H_);
    float* lamp   = alloc(M * H_);

    bf16* xb    = (bf16*)xbf;
    bf16* bufQ  = (bf16*)bufQf;
    bf16* bufK  = (bf16*)bufKf;
    bf16* obf   = (bf16*)obff;
    bf16* wqkvT = (bf16*)wqkvTf;                  // 12.58M bf16 elems
    bf16* wmidT = wqkvT;                          // [384,2048]  (after QKV gemm)
    bf16* wexpT = wqkvT + (size_t)384 * HID_;     // 3 x [2048,128]
    bf16* woT   = wqkvT;                          // [2048,2048] (after expands)
    float* midp = bufQKV;                         // 4 x [2048,384] fp32 (after conv)
    bf16*  midb = (bf16*)(bufQKV + 4 * M * 384);  // [2048,384] bf16

    dim3 blk(256);
    auto gemm = [&](const bf16* A, const bf16* Bt, const float* bias, void* C,
                    int Mm, int Nn, int Kk, int lda, int ldc, int ksplit,
                    int bf16out) {
        dim3 grid(Nn / 128, Mm / 128, ksplit ? Kk / ksplit : 1);
        int kf = Kk;
        mfma_gemm_kernel<<<grid, blk, 0, stream>>>(A, Bt, bias, C, Mm, Nn, kf,
                                                   lda, ldc, ksplit, bf16out);
    };
    auto tcast = [&](const float* W, bf16* Wt, int Kk, int Nn) {
        tcast_kernel<<<dim3(Nn / 32, Kk / 32), blk, 0, stream>>>(W, Wt, Kk, Nn);
    };

    // 0) cast x to bf16
    cast_bf16_kernel<<<dim3((unsigned)(M * HID_ / 8 / 256)), blk, 0, stream>>>(x, xb);

    // 1) fused QKV projection: N=6144, 768 blocks
    tcast(Wq, wqkvT,                         HID_, HID_);
    tcast(Wk, wqkvT + (size_t)HID_ * HID_,   HID_, HID_);
    tcast(Wv, wqkvT + (size_t)2 * HID_ * HID_, HID_, HID_);
    gemm(xb, wqkvT, nullptr, bufQKV, (int)M, 3 * HID_, HID_, HID_, 3 * HID_, 0, 0);

    // 2) conv + silu (+ l2norm); q/k -> bf16, v -> fp32
    conv_silu_kernel<<<dim3(B_ * T_), blk, 0, stream>>>(bufQKV, 3 * HID_, 0,
        conv_wq, bufQ, nullptr, 2);
    conv_silu_kernel<<<dim3(B_ * T_), blk, 0, stream>>>(bufQKV, 3 * HID_, HID_,
        conv_wk, bufK, nullptr, 1);
    conv_silu_kernel<<<dim3(B_ * T_), blk, 0, stream>>>(bufQKV, 3 * HID_, 2 * HID_,
        conv_wv, nullptr, bufV, 0);

    // 3) skinny heads bb/bd/lam
    skinny3_kernel<<<dim3((unsigned)(M / 16)), blk, 0, stream>>>(
        x, Wbb, Wbd, Wlam, bb, bd, lamp);

    // 4) fused mid GEMM: [Wgb1|Wgd1|Wg1], N=384, split-K=4 -> reduce to bf16
    tcast(Wgb1, wmidT,               HID_, DV_);
    tcast(Wgd1, wmidT + HID_ * DV_,  HID_, DV_);
    tcast(Wg1,  wmidT + 2 * HID_ * DV_, HID_, DV_);
    gemm(xb, wmidT, nullptr, midp, (int)M, 384, HID_, HID_, 384, 512, 0);
    mid_reduce_kernel<<<dim3((unsigned)(M * 384 / 4 / 256)), blk, 0, stream>>>(
        midp, midb);

    // 5) expand GEMMs (K=128)
    tcast(Wgb2, wexpT,                   DV_, HID_);
    tcast(Wgd2, wexpT + HID_ * DV_,      DV_, HID_);
    tcast(Wg2,  wexpT + 2 * HID_ * DV_,  DV_, HID_);
    gemm(midb,       wexpT,                  nullptr, bufA, (int)M, HID_, DV_, 384, HID_, 0, 0);
    gemm(midb + 128, wexpT + HID_ * DV_,     nullptr, bufB, (int)M, HID_, DV_, 384, HID_, 0, 0);
    gemm(midb + 256, wexpT + 2 * HID_ * DV_, bg2,     bufE, (int)M, HID_, DV_, 384, HID_, 0, 0);

    // 6) decay gates -> exp(gf), exp(gs) in place (fp32)
    decay_gate_kernel<<<dim3((unsigned)(M * HID_ / 256)), blk, 0, stream>>>(
        bufA, bufB, A_log, dt_bias);

    // 7) dual-state delta-rule recurrence (512 blocks)
    fkda_kernel<<<dim3(512), blk, 0, stream>>>(bufQ, bufK, bufV, bufA, bufB,
                                               bb, bd, bufC, bufD);

    // 8) mix + rmsnorm + gate -> bf16
    mix_norm_gate_kernel<<<dim3(B_ * T_), blk, 0, stream>>>(
        bufC, bufD, lamp, bufE, onorm_w, obf);

    // 9) output projection
    tcast(Wo, woT, HID_, HID_);
    gemm(obf, woT, nullptr, out, (int)M, HID_, HID_, HID_, HID_, 0, 0);
}

// Round 5
// 778.821 us; speedup vs baseline: 3.3961x; 1.2321x over previous
//
#include <hip/hip_runtime.h>
#include <hip/hip_bf16.h>
#include <math.h>
#include <stdint.h>

#define B_   2
#define T_   1024
#define HID_ 2048
#define H_   16
#define DK_  128
#define DV_  128
#define TS_  16     // timesteps staged per LDS tile in recurrence

typedef __bf16 bf16;
typedef __attribute__((ext_vector_type(8))) __bf16 bf16x8;
typedef __attribute__((ext_vector_type(4))) float f32x4;

typedef __attribute__((address_space(3))) uint32_t* lds_ptr_t;
typedef const __attribute__((address_space(1))) uint32_t* glb_ptr_t;

__device__ __forceinline__ float sigmoidf_(float x) {
    return 1.0f / (1.0f + __expf(-x));
}

// async global->LDS, 16B per lane. LDS base wave-uniform (HW: lane i ->
// base + 16*i); global address is per-lane.
__device__ __forceinline__ void ldg_to_lds16(const void* g, void* lds) {
    __builtin_amdgcn_global_load_lds((glb_ptr_t)(uintptr_t)g,
                                     (lds_ptr_t)(uintptr_t)lds, 16, 0, 0);
}

// DPP rotate-add: x += rotate_within_row16(x, n). VALU-latency cross-lane
// (vs ~120cyc ds_swizzle for __shfl_xor). CTRL = 0x120 + n (row_ror:n).
// dpp_ctrl must be an immediate -> template parameter.
template <int CTRL>
__device__ __forceinline__ float dpp_ror_add(float x) {
    int yi = __builtin_amdgcn_update_dpp(
        0, __builtin_bit_cast(int, x), CTRL, 0xF, 0xF, true);
    return x + __builtin_bit_cast(float, yi);
}
// all-reduce (sum) across the 16 lanes of a DPP row
__device__ __forceinline__ float row16_allreduce(float x) {
    x = dpp_ror_add<0x128>(x);   // ror 8
    x = dpp_ror_add<0x124>(x);   // ror 4
    x = dpp_ror_add<0x122>(x);   // ror 2
    x = dpp_ror_add<0x121>(x);   // ror 1
    return x;
}

// ---------------------------------------------------------------------------
// fp32 -> bf16 elementwise cast, 8 elems/thread
// ---------------------------------------------------------------------------
__global__ __launch_bounds__(256) void cast_bf16_kernel(
    const float* __restrict__ in, bf16* __restrict__ out)
{
    int i = blockIdx.x * 256 + threadIdx.x;
    float4 a = ((const float4*)in)[2 * i];
    float4 b = ((const float4*)in)[2 * i + 1];
    bf16x8 o;
    o[0] = (bf16)a.x; o[1] = (bf16)a.y; o[2] = (bf16)a.z; o[3] = (bf16)a.w;
    o[4] = (bf16)b.x; o[5] = (bf16)b.y; o[6] = (bf16)b.z; o[7] = (bf16)b.w;
    ((bf16x8*)out)[i] = o;
}

// ---------------------------------------------------------------------------
// W [K,N] fp32  ->  Wt [N,K] bf16 (transpose-cast). 32x32 tiles.
// ---------------------------------------------------------------------------
__global__ __launch_bounds__(256) void tcast_kernel(
    const float* __restrict__ W, bf16* __restrict__ Wt, int K, int N)
{
    __shared__ float tile[32][33];
    const int k0 = blockIdx.y * 32, n0 = blockIdx.x * 32;
    const int r = threadIdx.x >> 5, c = threadIdx.x & 31;
    #pragma unroll
    for (int i = 0; i < 4; ++i)
        tile[r + 8 * i][c] = W[(size_t)(k0 + r + 8 * i) * N + n0 + c];
    __syncthreads();
    #pragma unroll
    for (int i = 0; i < 4; ++i)
        Wt[(size_t)(n0 + r + 8 * i) * K + k0 + c] = (bf16)tile[c][r + 8 * i];
}

// ---------------------------------------------------------------------------
// bf16 MFMA GEMM: C[M,N] = A[M,K] @ Bt[N,K]^T (+bias). 128x128 tile, BK=32.
// lda/ldc = element row strides of A/C; Bt row stride = Kfull.
// ksplit>0: blockIdx.z handles K-range [z*ksplit, (z+1)*ksplit), writes to
// plane Cout + z*M*N (fp32).
// ---------------------------------------------------------------------------
__global__ __launch_bounds__(256) void mfma_gemm_kernel(
    const bf16* __restrict__ A, const bf16* __restrict__ Bt,
    const float* __restrict__ bias, void* __restrict__ Cout,
    int M, int N, int Kfull, int lda, int ldc, int ksplit, int bf16out)
{
    __shared__ bf16 As[128 * 32];
    __shared__ bf16 Bs[128 * 32];

    const int tid  = threadIdx.x;
    const int w    = tid >> 6;
    const int lane = tid & 63;
    const int n0   = blockIdx.x * 128;
    const int m0   = blockIdx.y * 128;
    const int wm   = (w >> 1) * 64;
    const int wn   = (w & 1) * 64;

    int kbeg = 0, kend = Kfull;
    float* Cf = (float*)Cout;
    if (ksplit > 0) {
        kbeg = blockIdx.z * ksplit;
        kend = kbeg + ksplit;
        Cf  += (size_t)blockIdx.z * M * N;
    }

    const int lr = lane >> 2;
    const int lc = (lane & 3) * 8;

    f32x4 acc[4][4];
    #pragma unroll
    for (int i = 0; i < 4; ++i)
        #pragma unroll
        for (int j = 0; j < 4; ++j) acc[i][j] = (f32x4)0.0f;

    const bf16* ApL = As + (wm + (lane & 15)) * 32 + (lane >> 4) * 8;
    const bf16* BpL = Bs + (wn + (lane & 15)) * 32 + (lane >> 4) * 8;

    for (int k0 = kbeg; k0 < kend; k0 += 32) {
        #pragma unroll
        for (int i = 0; i < 2; ++i) {
            const int rr = (w * 2 + i) * 16 + lr;
            ldg_to_lds16(A  + (size_t)(m0 + rr) * lda   + k0 + lc, As + (w * 2 + i) * 512);
            ldg_to_lds16(Bt + (size_t)(n0 + rr) * Kfull + k0 + lc, Bs + (w * 2 + i) * 512);
        }
        __syncthreads();

        bf16x8 af[4], bfr[4];
        #pragma unroll
        for (int i = 0; i < 4; ++i) af[i]  = *(const bf16x8*)(ApL + i * 16 * 32);
        #pragma unroll
        for (int j = 0; j < 4; ++j) bfr[j] = *(const bf16x8*)(BpL + j * 16 * 32);
        #pragma unroll
        for (int i = 0; i < 4; ++i)
            #pragma unroll
            for (int j = 0; j < 4; ++j)
                acc[i][j] = __builtin_amdgcn_mfma_f32_16x16x32_bf16(
                    af[i], bfr[j], acc[i][j], 0, 0, 0);
        __syncthreads();
    }

    #pragma unroll
    for (int i = 0; i < 4; ++i) {
        const int row = m0 + wm + i * 16 + (lane >> 4) * 4;
        #pragma unroll
        for (int j = 0; j < 4; ++j) {
            const int col = n0 + wn + j * 16 + (lane & 15);
            const float bv = bias ? bias[col] : 0.0f;
            #pragma unroll
            for (int r = 0; r < 4; ++r) {
                float v = acc[i][j][r] + bv;
                if (bf16out) ((bf16*)Cout)[(size_t)(row + r) * ldc + col] = (bf16)v;
                else         Cf[(size_t)(row + r) * ldc + col] = v;
            }
        }
    }
}

// ---------------------------------------------------------------------------
// Sum 4 split-K fp32 planes [M,384] -> bf16
// ---------------------------------------------------------------------------
__global__ __launch_bounds__(256) void mid_reduce_kernel(
    const float* __restrict__ midp, bf16* __restrict__ midb)
{
    const size_t plane = (size_t)2048 * 384 / 4;   // float4s per plane
    size_t i = (size_t)blockIdx.x * 256 + threadIdx.x;
    float4 a = ((const float4*)midp)[i];
    float4 b = ((const float4*)midp)[i + plane];
    float4 c = ((const float4*)midp)[i + 2 * plane];
    float4 d = ((const float4*)midp)[i + 3 * plane];
    float4 s;
    s.x = a.x + b.x + c.x + d.x; s.y = a.y + b.y + c.y + d.y;
    s.z = a.z + b.z + c.z + d.z; s.w = a.w + b.w + c.w + d.w;
    bf16 o[4] = {(bf16)s.x, (bf16)s.y, (bf16)s.z, (bf16)s.w};
    *(uint64_t*)(midb + 4 * i) = *(uint64_t*)o;
}

// ---------------------------------------------------------------------------
// Fused skinny GEMMs: bb/bd/lam = x @ {Wbb,Wbd,Wlam}  (N=16 each, K=2048).
// ---------------------------------------------------------------------------
__global__ __launch_bounds__(256) void skinny3_kernel(
    const float* __restrict__ x, const float* __restrict__ Wbb,
    const float* __restrict__ Wbd, const float* __restrict__ Wlam,
    float* __restrict__ bb, float* __restrict__ bd, float* __restrict__ lam)
{
    __shared__ float xs[16][128];
    __shared__ float wsh[128][48];
    const int m0  = blockIdx.x * 16;
    const int tid = threadIdx.x;
    const int r = tid >> 4, cg = tid & 15;
    float acc0 = 0.f, acc1 = 0.f, acc2 = 0.f;

    for (int k0 = 0; k0 < HID_; k0 += 128) {
        __syncthreads();
        #pragma unroll
        for (int i = 0; i < 2; ++i) {
            int f = tid + 256 * i;
            int rr = f >> 5, cc = (f & 31) * 4;
            *(float4*)&xs[rr][cc] = *(const float4*)(x + (size_t)(m0 + rr) * HID_ + k0 + cc);
        }
        #pragma unroll
        for (int i = 0; i < 2; ++i) {
            int f = tid + 256 * i;
            int kk = f >> 2, cc = (f & 3) * 4;
            *(float4*)&wsh[kk][cc]      = *(const float4*)(Wbb  + (size_t)(k0 + kk) * 16 + cc);
            *(float4*)&wsh[kk][16 + cc] = *(const float4*)(Wbd  + (size_t)(k0 + kk) * 16 + cc);
            *(float4*)&wsh[kk][32 + cc] = *(const float4*)(Wlam + (size_t)(k0 + kk) * 16 + cc);
        }
        __syncthreads();
        #pragma unroll 8
        for (int kk = 0; kk < 128; ++kk) {
            float xv = xs[r][kk];
            acc0 += xv * wsh[kk][cg];
            acc1 += xv * wsh[kk][16 + cg];
            acc2 += xv * wsh[kk][32 + cg];
        }
    }
    size_t o = (size_t)(m0 + r) * 16 + cg;
    bb[o] = acc0; bd[o] = acc1; lam[o] = acc2;
}

// ---------------------------------------------------------------------------
// Causal depthwise conv1d (K=4) + SiLU, + optional per-head l2norm.
// Reads strided slice of fused QKV pre-activations (row stride ldx, col off).
// mode: 0 = silu only -> fp32 out (v); 1 = + l2norm -> bf16 (k);
//       2 = + l2norm * DK^-0.5 -> bf16 (q)
// ---------------------------------------------------------------------------
__global__ __launch_bounds__(256) void conv_silu_kernel(
    const float* __restrict__ xin, int ldx, int coloff,
    const float* __restrict__ w,
    bf16* __restrict__ ybf, float* __restrict__ yf32, int mode)
{
    const int bt  = blockIdx.x;
    const int t   = bt & (T_ - 1);
    const int tid = threadIdx.x;
    const float* xr = xin + (size_t)bt * ldx + coloff;

    float val[8];
    #pragma unroll
    for (int jj = 0; jj < 8; ++jj) {
        int c = tid + 256 * jj;
        float4 wc = *(const float4*)(w + (size_t)c * 4);
        const float* xc = xr + c;
        float acc = wc.w * xc[0];
        if (t >= 1) acc += wc.z * xc[-ldx];
        if (t >= 2) acc += wc.y * xc[-2 * ldx];
        if (t >= 3) acc += wc.x * xc[-3 * ldx];
        val[jj] = acc * sigmoidf_(acc);
    }

    if (mode > 0) {
        __shared__ float red[4][8];
        const int wv = tid >> 6;
        #pragma unroll
        for (int jj = 0; jj < 8; ++jj) {
            float v2 = val[jj] * val[jj];
            #pragma unroll
            for (int m = 1; m < 64; m <<= 1) v2 += __shfl_xor(v2, m);
            if ((tid & 63) == 0) red[wv][jj] = v2;
        }
        __syncthreads();
        const int wb = (tid >> 7) * 2;
        #pragma unroll
        for (int jj = 0; jj < 8; ++jj) {
            float ss = red[wb][jj] + red[wb + 1][jj];
            float sc = rsqrtf(ss + 1e-6f);
            if (mode == 2) sc *= 0.08838834764831845f;     // DK^-0.5
            val[jj] *= sc;
        }
    }

    const size_t row = (size_t)bt * HID_;
    if (mode == 0) {
        #pragma unroll
        for (int jj = 0; jj < 8; ++jj)
            yf32[row + tid + 256 * jj] = val[jj];
    } else {
        #pragma unroll
        for (int jj = 0; jj < 8; ++jj)
            ybf[row + tid + 256 * jj] = (bf16)val[jj];
    }
}

// ---------------------------------------------------------------------------
// Decay gates: in-place  gb <- exp(gf), gd <- exp(gs)   (fp32 throughout)
// ---------------------------------------------------------------------------
__global__ __launch_bounds__(256) void decay_gate_kernel(
    float* gb, float* gd,
    const float* __restrict__ A_log, const float* __restrict__ dt_bias)
{
    size_t i = (size_t)blockIdx.x * 256 + threadIdx.x;
    int c = (int)(i & (HID_ - 1));
    int h = c >> 7;
    float a  = gb[i];
    float d  = gd[i];
    float na = -__expf(A_log[h]);
    float db = dt_bias[c];
    float xf = a + d + db;
    float xs = a - d + db;
    float spf = (xf > 20.0f) ? xf : log1pf(__expf(xf));
    float sps = (xs > 20.0f) ? xs : log1pf(__expf(xs));
    gb[i] = __expf(na * spf);
    gd[i] = __expf(na * sps);
}

// ---------------------------------------------------------------------------
// Dual-state gated delta-rule recurrence, v3: DPP row-reduce.
// Grid: 512 blocks: bx = sv*32 + bh;  bh = b*16+h, sv = s*8+vc.
// Block: 256 threads = 4 waves; wave = 4 cols x 16 ksegs (8 k's each);
// the 16 ksegs of one column are exactly one DPP row of 16 lanes.
// S[8] fp32 per thread. q/k staged bf16, eg fp32, via global_load_lds.
// Critical chain per step: decay-mul + dot + 4 DPP adds (~4cyc each) + write;
// replaces 4x ds_swizzle (~120cyc each) from v2.
// ---------------------------------------------------------------------------
__global__ __launch_bounds__(256) void fkda_kernel(
    const bf16* __restrict__ qp, const bf16* __restrict__ kp,
    const float* __restrict__ vp, const float* __restrict__ egf,
    const float* __restrict__ egs, const float* __restrict__ bbp,
    const float* __restrict__ bdp,
    float* __restrict__ ofp, float* __restrict__ osp)
{
    const int bx = blockIdx.x;
    const int bh = bx & 31;
    const int sv = bx >> 5;
    const int b  = bh >> 4;
    const int h  = bh & 15;
    const int s  = sv >> 3;
    const int vc = sv & 7;

    const float* eg = s ? egs : egf;
    float*       op = s ? osp : ofp;
    const float  bsign = s ? -1.0f : 1.0f;

    const int tid  = threadIdx.x;
    const int lane = tid & 63;
    const int w    = tid >> 6;
    const int kseg = lane & 15;             // 8 k's each: kseg*8
    const int colb = w * 4 + (lane >> 4);   // 0..15 within block

    const size_t base = (size_t)b * T_ * HID_ + (size_t)h * DK_;  // + t*HID_

    __shared__ float EG[TS_ * 128];     // 8 KB
    __shared__ bf16  KK[TS_ * 128];     // 4 KB
    __shared__ bf16  QQ[TS_ * 128];     // 4 KB
    __shared__ float VV[TS_ * 16];      // 1 KB
    __shared__ float OT[TS_ * 16];      // 1 KB
    __shared__ float BT[TS_];

    float S[8];
    #pragma unroll
    for (int j = 0; j < 8; ++j) S[j] = 0.0f;

    for (int t0 = 0; t0 < T_; t0 += TS_) {
        // ---- stage tile ----
        #pragma unroll
        for (int i = 0; i < 2; ++i) {
            int n = w * 2 + i;
            int f = n * 64 + lane;
            int tt = f >> 5, co = (f & 31) * 4;
            ldg_to_lds16(eg + base + (size_t)(t0 + tt) * HID_ + co, EG + n * 256);
        }
        {
            int f = w * 64 + lane;
            int tt = f >> 4, co = (f & 15) * 8;
            size_t g = base + (size_t)(t0 + tt) * HID_ + co;
            ldg_to_lds16(kp + g, KK + w * 512);
            ldg_to_lds16(qp + g, QQ + w * 512);
        }
        if (tid < 64) {       // V: 16t x 16cols fp32
            int tt = tid >> 2, vo = (tid & 3) * 4;
            size_t g = base + (size_t)(t0 + tt) * HID_ + vc * 16 + vo;
            ((float4*)VV)[tid] = *(const float4*)(vp + g);
        }
        if (tid < TS_) {
            size_t gi = ((size_t)b * T_ + t0 + tid) * H_ + h;
            BT[tid] = sigmoidf_(bbp[gi] + bsign * bdp[gi]);
        }
        __syncthreads();

        // ---- 16 sequential steps ----
        for (int tt = 0; tt < TS_; ++tt) {
            float e[8];
            *(float4*)&e[0] = *(const float4*)(EG + tt * 128 + kseg * 8);
            *(float4*)&e[4] = *(const float4*)(EG + tt * 128 + kseg * 8 + 4);
            bf16x8 k8 = *(const bf16x8*)(KK + tt * 128 + kseg * 8);
            bf16x8 q8 = *(const bf16x8*)(QQ + tt * 128 + kseg * 8);
            float vcol = VV[tt * 16 + colb];
            float btv  = BT[tt];

            float kf[8];
            #pragma unroll
            for (int j = 0; j < 8; ++j) kf[j] = (float)k8[j];

            // decay + k.S dot (two partial chains to shorten dep depth)
            float p0 = 0.0f, p1 = 0.0f;
            #pragma unroll
            for (int j = 0; j < 8; j += 2) {
                S[j]     *= e[j];     p0 += kf[j]     * S[j];
                S[j + 1] *= e[j + 1]; p1 += kf[j + 1] * S[j + 1];
            }
            float p = row16_allreduce(p0 + p1);

            float u = btv * (vcol - p);

            float o0 = 0.0f, o1 = 0.0f;
            #pragma unroll
            for (int j = 0; j < 8; j += 2) {
                S[j]     += kf[j]     * u; o0 += (float)q8[j]     * S[j];
                S[j + 1] += kf[j + 1] * u; o1 += (float)q8[j + 1] * S[j + 1];
            }
            float oo = row16_allreduce(o0 + o1);

            if ((lane & 15) == 0) OT[tt * 16 + colb] = oo;
        }
        __syncthreads();

        // ---- flush 16x16 outputs ----
        if (tid < 64) {
            int tt = tid >> 2, vo = (tid & 3) * 4;
            size_t g = base + (size_t)(t0 + tt) * HID_ + vc * 16 + vo;
            *(float4*)(op + g) = ((const float4*)OT)[tid];
        }
        // next-iter staging writes EG/KK/QQ/VV (disjoint from OT);
        // post-stage __syncthreads covers the OT flush reads.
    }
}

// ---------------------------------------------------------------------------
// o = lam*o_f + (1-lam)*o_s -> per-head RMSNorm * onorm_w -> * sigmoid(gate)
// ---------------------------------------------------------------------------
__global__ __launch_bounds__(256) void mix_norm_gate_kernel(
    const float* of, const float* os, const float* lam_pre,
    const float* gate, const float* onorm_w, bf16* outp)
{
    const int bt  = blockIdx.x;
    const int tid = threadIdx.x;
    const size_t row = (size_t)bt * HID_;

    float val[8];
    #pragma unroll
    for (int jj = 0; jj < 8; ++jj) {
        int c = tid + 256 * jj;
        int h = c >> 7;
        float l = sigmoidf_(lam_pre[(size_t)bt * H_ + h]);
        val[jj] = l * of[row + c] + (1.0f - l) * os[row + c];
    }

    __shared__ float red[4][8];
    const int wv = tid >> 6;
    #pragma unroll
    for (int jj = 0; jj < 8; ++jj) {
        float v2 = val[jj] * val[jj];
        #pragma unroll
        for (int m = 1; m < 64; m <<= 1) v2 += __shfl_xor(v2, m);
        if ((tid & 63) == 0) red[wv][jj] = v2;
    }
    __syncthreads();
    const int wb = (tid >> 7) * 2;
    #pragma unroll
    for (int jj = 0; jj < 8; ++jj) {
        int c = tid + 256 * jj;
        float ss   = red[wb][jj] + red[wb + 1][jj];
        float mean = ss * (1.0f / 128.0f);
        float sc   = rsqrtf(mean + 1e-5f) * onorm_w[c & 127];
        float g    = sigmoidf_(gate[row + c]);
        outp[row + c] = (bf16)(val[jj] * sc * g);
    }
}

// ---------------------------------------------------------------------------
extern "C" void kernel_launch(void* const* d_in, const int* in_sizes, int n_in,
                              void* d_out, int out_size, void* d_ws, size_t ws_size,
                              hipStream_t stream) {
    const float* x       = (const float*)d_in[0];
    const float* Wq      = (const float*)d_in[1];
    const float* Wk      = (const float*)d_in[2];
    const float* Wv      = (const float*)d_in[3];
    const float* conv_wq = (const float*)d_in[4];
    const float* conv_wk = (const float*)d_in[5];
    const float* conv_wv = (const float*)d_in[6];
    const float* Wgb1    = (const float*)d_in[7];
    const float* Wgb2    = (const float*)d_in[8];
    const float* Wgd1    = (const float*)d_in[9];
    const float* Wgd2    = (const float*)d_in[10];
    const float* Wbb     = (const float*)d_in[11];
    const float* Wbd     = (const float*)d_in[12];
    const float* Wlam    = (const float*)d_in[13];
    const float* A_log   = (const float*)d_in[14];
    const float* dt_bias = (const float*)d_in[15];
    const float* Wg1     = (const float*)d_in[16];
    const float* Wg2     = (const float*)d_in[17];
    const float* bg2     = (const float*)d_in[18];
    const float* onorm_w = (const float*)d_in[19];
    const float* Wo      = (const float*)d_in[20];
    float* out = (float*)d_out;

    const size_t M = (size_t)B_ * T_;   // 2048

    float* ws = (float*)d_ws;
    size_t off = 0;
    auto alloc = [&](size_t nfloats) { float* p = ws + off; off += nfloats; return p; };

    float* bufQKV = alloc(M * 3 * HID_);          // QKV preacts; later midp+midb
    float* wqkvTf = alloc(M * 3 * HID_ / 2);      // [6144,2048] bf16; later wmid/wexp/wo
    float* xbf    = alloc(M * HID_ / 2);
    float* bufQf  = alloc(M * HID_ / 2);          // q bf16
    float* bufKf  = alloc(M * HID_ / 2);          // k bf16
    float* bufV   = alloc(M * HID_);
    float* bufA   = alloc(M * HID_);              // g_base -> exp(gf)
    float* bufB   = alloc(M * HID_);              // g_delta -> exp(gs)
    float* bufC   = alloc(M * HID_);              // o_f
    float* bufD   = alloc(M * HID_);              // o_s
    float* bufE   = alloc(M * HID_);              // gate
    float* obff   = alloc(M * HID_ / 2);
    float* bb     = alloc(M * H_);
    float* bd     = alloc(M * H_);
    float* lamp   = alloc(M * H_);

    bf16* xb    = (bf16*)xbf;
    bf16* bufQ  = (bf16*)bufQf;
    bf16* bufK  = (bf16*)bufKf;
    bf16* obf   = (bf16*)obff;
    bf16* wqkvT = (bf16*)wqkvTf;                  // 12.58M bf16 elems
    bf16* wmidT = wqkvT;                          // [384,2048]  (after QKV gemm)
    bf16* wexpT = wqkvT + (size_t)384 * HID_;     // 3 x [2048,128]
    bf16* woT   = wqkvT;                          // [2048,2048] (after expands)
    float* midp = bufQKV;                         // 4 x [2048,384] fp32 (after conv)
    bf16*  midb = (bf16*)(bufQKV + 4 * M * 384);  // [2048,384] bf16

    dim3 blk(256);
    auto gemm = [&](const bf16* A, const bf16* Bt, const float* bias, void* C,
                    int Mm, int Nn, int Kk, int lda, int ldc, int ksplit,
                    int bf16out) {
        dim3 grid(Nn / 128, Mm / 128, ksplit ? Kk / ksplit : 1);
        int kf = Kk;
        mfma_gemm_kernel<<<grid, blk, 0, stream>>>(A, Bt, bias, C, Mm, Nn, kf,
                                                   lda, ldc, ksplit, bf16out);
    };
    auto tcast = [&](const float* W, bf16* Wt, int Kk, int Nn) {
        tcast_kernel<<<dim3(Nn / 32, Kk / 32), blk, 0, stream>>>(W, Wt, Kk, Nn);
    };

    // 0) cast x to bf16
    cast_bf16_kernel<<<dim3((unsigned)(M * HID_ / 8 / 256)), blk, 0, stream>>>(x, xb);

    // 1) fused QKV projection: N=6144, 768 blocks
    tcast(Wq, wqkvT,                         HID_, HID_);
    tcast(Wk, wqkvT + (size_t)HID_ * HID_,   HID_, HID_);
    tcast(Wv, wqkvT + (size_t)2 * HID_ * HID_, HID_, HID_);
    gemm(xb, wqkvT, nullptr, bufQKV, (int)M, 3 * HID_, HID_, HID_, 3 * HID_, 0, 0);

    // 2) conv + silu (+ l2norm); q/k -> bf16, v -> fp32
    conv_silu_kernel<<<dim3(B_ * T_), blk, 0, stream>>>(bufQKV, 3 * HID_, 0,
        conv_wq, bufQ, nullptr, 2);
    conv_silu_kernel<<<dim3(B_ * T_), blk, 0, stream>>>(bufQKV, 3 * HID_, HID_,
        conv_wk, bufK, nullptr, 1);
    conv_silu_kernel<<<dim3(B_ * T_), blk, 0, stream>>>(bufQKV, 3 * HID_, 2 * HID_,
        conv_wv, nullptr, bufV, 0);

    // 3) skinny heads bb/bd/lam
    skinny3_kernel<<<dim3((unsigned)(M / 16)), blk, 0, stream>>>(
        x, Wbb, Wbd, Wlam, bb, bd, lamp);

    // 4) fused mid GEMM: [Wgb1|Wgd1|Wg1], N=384, split-K=4 -> reduce to bf16
    tcast(Wgb1, wmidT,               HID_, DV_);
    tcast(Wgd1, wmidT + HID_ * DV_,  HID_, DV_);
    tcast(Wg1,  wmidT + 2 * HID_ * DV_, HID_, DV_);
    gemm(xb, wmidT, nullptr, midp, (int)M, 384, HID_, HID_, 384, 512, 0);
    mid_reduce_kernel<<<dim3((unsigned)(M * 384 / 4 / 256)), blk, 0, stream>>>(
        midp, midb);

    // 5) expand GEMMs (K=128)
    tcast(Wgb2, wexpT,                   DV_, HID_);
    tcast(Wgd2, wexpT + HID_ * DV_,      DV_, HID_);
    tcast(Wg2,  wexpT + 2 * HID_ * DV_,  DV_, HID_);
    gemm(midb,       wexpT,                  nullptr, bufA, (int)M, HID_, DV_, 384, HID_, 0, 0);
    gemm(midb + 128, wexpT + HID_ * DV_,     nullptr, bufB, (int)M, HID_, DV_, 384, HID_, 0, 0);
    gemm(midb + 256, wexpT + 2 * HID_ * DV_, bg2,     bufE, (int)M, HID_, DV_, 384, HID_, 0, 0);

    // 6) decay gates -> exp(gf), exp(gs) in place (fp32)
    decay_gate_kernel<<<dim3((unsigned)(M * HID_ / 256)), blk, 0, stream>>>(
        bufA, bufB, A_log, dt_bias);

    // 7) dual-state delta-rule recurrence (512 blocks)
    fkda_kernel<<<dim3(512), blk, 0, stream>>>(bufQ, bufK, bufV, bufA, bufB,
                                               bb, bd, bufC, bufD);

    // 8) mix + rmsnorm + gate -> bf16
    mix_norm_gate_kernel<<<dim3(B_ * T_), blk, 0, stream>>>(
        bufC, bufD, lamp, bufE, onorm_w, obf);

    // 9) output projection
    tcast(Wo, woT, HID_, HID_);
    gemm(obf, woT, nullptr, out, (int)M, HID_, HID_, HID_, HID_, 0, 0);
}

// Round 6
// 751.137 us; speedup vs baseline: 3.5213x; 1.0369x over previous
//
#include <hip/hip_runtime.h>
#include <hip/hip_bf16.h>
#include <math.h>
#include <stdint.h>

#define B_   2
#define T_   1024
#define HID_ 2048
#define H_   16
#define DK_  128
#define DV_  128
#define TS_  16     // timesteps staged per LDS tile in recurrence

typedef __bf16 bf16;
typedef __attribute__((ext_vector_type(8))) __bf16 bf16x8;
typedef __attribute__((ext_vector_type(4))) float f32x4;

typedef __attribute__((address_space(3))) uint32_t* lds_ptr_t;
typedef const __attribute__((address_space(1))) uint32_t* glb_ptr_t;

__device__ __forceinline__ float sigmoidf_(float x) {
    return 1.0f / (1.0f + __expf(-x));
}

// async global->LDS, 16B per lane. LDS base wave-uniform (HW: lane i ->
// base + 16*i); global address is per-lane.
__device__ __forceinline__ void ldg_to_lds16(const void* g, void* lds) {
    __builtin_amdgcn_global_load_lds((glb_ptr_t)(uintptr_t)g,
                                     (lds_ptr_t)(uintptr_t)lds, 16, 0, 0);
}

// DPP rotate-add: VALU-latency cross-lane. CTRL = 0x120 + n (row_ror:n).
template <int CTRL>
__device__ __forceinline__ float dpp_ror_add(float x) {
    int yi = __builtin_amdgcn_update_dpp(
        0, __builtin_bit_cast(int, x), CTRL, 0xF, 0xF, true);
    return x + __builtin_bit_cast(float, yi);
}
// all-reduce (sum) across the 16 lanes of a DPP row
__device__ __forceinline__ float row16_allreduce(float x) {
    x = dpp_ror_add<0x128>(x);   // ror 8
    x = dpp_ror_add<0x124>(x);   // ror 4
    x = dpp_ror_add<0x122>(x);   // ror 2
    x = dpp_ror_add<0x121>(x);   // ror 1
    return x;
}

// ---------------------------------------------------------------------------
// fp32 -> bf16 elementwise cast, 8 elems/thread
// ---------------------------------------------------------------------------
__global__ __launch_bounds__(256) void cast_bf16_kernel(
    const float* __restrict__ in, bf16* __restrict__ out)
{
    int i = blockIdx.x * 256 + threadIdx.x;
    float4 a = ((const float4*)in)[2 * i];
    float4 b = ((const float4*)in)[2 * i + 1];
    bf16x8 o;
    o[0] = (bf16)a.x; o[1] = (bf16)a.y; o[2] = (bf16)a.z; o[3] = (bf16)a.w;
    o[4] = (bf16)b.x; o[5] = (bf16)b.y; o[6] = (bf16)b.z; o[7] = (bf16)b.w;
    ((bf16x8*)out)[i] = o;
}

// ---------------------------------------------------------------------------
// W [K,N] fp32  ->  Wt [N,K] bf16 (transpose-cast). 32x32 tiles.
// ---------------------------------------------------------------------------
__global__ __launch_bounds__(256) void tcast_kernel(
    const float* __restrict__ W, bf16* __restrict__ Wt, int K, int N)
{
    __shared__ float tile[32][33];
    const int k0 = blockIdx.y * 32, n0 = blockIdx.x * 32;
    const int r = threadIdx.x >> 5, c = threadIdx.x & 31;
    #pragma unroll
    for (int i = 0; i < 4; ++i)
        tile[r + 8 * i][c] = W[(size_t)(k0 + r + 8 * i) * N + n0 + c];
    __syncthreads();
    #pragma unroll
    for (int i = 0; i < 4; ++i)
        Wt[(size_t)(n0 + r + 8 * i) * K + k0 + c] = (bf16)tile[c][r + 8 * i];
}

// ---------------------------------------------------------------------------
// Transpose-cast with row/col offset + sign into Wt with row-stride 256.
// W [128, N] fp32 -> Wt[(noff+n)*256 + koff + k] = sign * W[k][n].
// Used to build [Wgb2; +/-Wgd2] concatenated K=256 weights.
// ---------------------------------------------------------------------------
__global__ __launch_bounds__(256) void tcast_off_kernel(
    const float* __restrict__ W, bf16* __restrict__ Wt,
    int N, int noff, int koff, float sign)
{
    __shared__ float tile[32][33];
    const int k0 = blockIdx.y * 32, n0 = blockIdx.x * 32;
    const int r = threadIdx.x >> 5, c = threadIdx.x & 31;
    #pragma unroll
    for (int i = 0; i < 4; ++i)
        tile[r + 8 * i][c] = W[(size_t)(k0 + r + 8 * i) * N + n0 + c];
    __syncthreads();
    #pragma unroll
    for (int i = 0; i < 4; ++i)
        Wt[(size_t)(noff + n0 + r + 8 * i) * 256 + koff + k0 + c] =
            (bf16)(sign * tile[c][r + 8 * i]);
}

// ---------------------------------------------------------------------------
// bf16 MFMA GEMM: C[M,N] = A[M,K] @ Bt[N,K]^T (+bias). 128x128 tile, BK=32.
// lda/ldc = element row strides of A/C; Bt row stride = Kfull.
// ---------------------------------------------------------------------------
__global__ __launch_bounds__(256) void mfma_gemm_kernel(
    const bf16* __restrict__ A, const bf16* __restrict__ Bt,
    const float* __restrict__ bias, void* __restrict__ Cout,
    int M, int N, int Kfull, int lda, int ldc, int bf16out)
{
    __shared__ bf16 As[128 * 32];
    __shared__ bf16 Bs[128 * 32];

    const int tid  = threadIdx.x;
    const int w    = tid >> 6;
    const int lane = tid & 63;
    const int n0   = blockIdx.x * 128;
    const int m0   = blockIdx.y * 128;
    const int wm   = (w >> 1) * 64;
    const int wn   = (w & 1) * 64;

    const int lr = lane >> 2;
    const int lc = (lane & 3) * 8;

    f32x4 acc[4][4];
    #pragma unroll
    for (int i = 0; i < 4; ++i)
        #pragma unroll
        for (int j = 0; j < 4; ++j) acc[i][j] = (f32x4)0.0f;

    const bf16* ApL = As + (wm + (lane & 15)) * 32 + (lane >> 4) * 8;
    const bf16* BpL = Bs + (wn + (lane & 15)) * 32 + (lane >> 4) * 8;

    for (int k0 = 0; k0 < Kfull; k0 += 32) {
        #pragma unroll
        for (int i = 0; i < 2; ++i) {
            const int rr = (w * 2 + i) * 16 + lr;
            ldg_to_lds16(A  + (size_t)(m0 + rr) * lda   + k0 + lc, As + (w * 2 + i) * 512);
            ldg_to_lds16(Bt + (size_t)(n0 + rr) * Kfull + k0 + lc, Bs + (w * 2 + i) * 512);
        }
        __syncthreads();

        bf16x8 af[4], bfr[4];
        #pragma unroll
        for (int i = 0; i < 4; ++i) af[i]  = *(const bf16x8*)(ApL + i * 16 * 32);
        #pragma unroll
        for (int j = 0; j < 4; ++j) bfr[j] = *(const bf16x8*)(BpL + j * 16 * 32);
        #pragma unroll
        for (int i = 0; i < 4; ++i)
            #pragma unroll
            for (int j = 0; j < 4; ++j)
                acc[i][j] = __builtin_amdgcn_mfma_f32_16x16x32_bf16(
                    af[i], bfr[j], acc[i][j], 0, 0, 0);
        __syncthreads();
    }

    #pragma unroll
    for (int i = 0; i < 4; ++i) {
        const int row = m0 + wm + i * 16 + (lane >> 4) * 4;
        #pragma unroll
        for (int j = 0; j < 4; ++j) {
            const int col = n0 + wn + j * 16 + (lane & 15);
            const float bv = bias ? bias[col] : 0.0f;
            #pragma unroll
            for (int r = 0; r < 4; ++r) {
                float v = acc[i][j][r] + bv;
                if (bf16out) ((bf16*)Cout)[(size_t)(row + r) * ldc + col] = (bf16)v;
                else ((float*)Cout)[(size_t)(row + r) * ldc + col] = v;
            }
        }
    }
}

// ---------------------------------------------------------------------------
// Cast mid slice of mega-GEMM output (cols 6144..6527 of [M,6528]) -> bf16
// midb [M,384]. 4 cols/thread.
// ---------------------------------------------------------------------------
__global__ __launch_bounds__(256) void midcast_kernel(
    const float* __restrict__ src, bf16* __restrict__ midb)
{
    int i = blockIdx.x * 256 + threadIdx.x;   // over 2048*96
    int m = i / 96, c4 = i - m * 96;
    float4 v = *(const float4*)(src + (size_t)m * 6528 + 6144 + c4 * 4);
    bf16 o[4] = {(bf16)v.x, (bf16)v.y, (bf16)v.z, (bf16)v.w};
    *(uint64_t*)(midb + (size_t)m * 384 + c4 * 4) = *(uint64_t*)o;
}

// ---------------------------------------------------------------------------
// Fused skinny GEMMs: bb/bd/lam = x @ {Wbb,Wbd,Wlam}  (N=16 each, K=2048).
// ---------------------------------------------------------------------------
__global__ __launch_bounds__(256) void skinny3_kernel(
    const float* __restrict__ x, const float* __restrict__ Wbb,
    const float* __restrict__ Wbd, const float* __restrict__ Wlam,
    float* __restrict__ bb, float* __restrict__ bd, float* __restrict__ lam)
{
    __shared__ float xs[16][128];
    __shared__ float wsh[128][48];
    const int m0  = blockIdx.x * 16;
    const int tid = threadIdx.x;
    const int r = tid >> 4, cg = tid & 15;
    float acc0 = 0.f, acc1 = 0.f, acc2 = 0.f;

    for (int k0 = 0; k0 < HID_; k0 += 128) {
        __syncthreads();
        #pragma unroll
        for (int i = 0; i < 2; ++i) {
            int f = tid + 256 * i;
            int rr = f >> 5, cc = (f & 31) * 4;
            *(float4*)&xs[rr][cc] = *(const float4*)(x + (size_t)(m0 + rr) * HID_ + k0 + cc);
        }
        #pragma unroll
        for (int i = 0; i < 2; ++i) {
            int f = tid + 256 * i;
            int kk = f >> 2, cc = (f & 3) * 4;
            *(float4*)&wsh[kk][cc]      = *(const float4*)(Wbb  + (size_t)(k0 + kk) * 16 + cc);
            *(float4*)&wsh[kk][16 + cc] = *(const float4*)(Wbd  + (size_t)(k0 + kk) * 16 + cc);
            *(float4*)&wsh[kk][32 + cc] = *(const float4*)(Wlam + (size_t)(k0 + kk) * 16 + cc);
        }
        __syncthreads();
        #pragma unroll 8
        for (int kk = 0; kk < 128; ++kk) {
            float xv = xs[r][kk];
            acc0 += xv * wsh[kk][cg];
            acc1 += xv * wsh[kk][16 + cg];
            acc2 += xv * wsh[kk][32 + cg];
        }
    }
    size_t o = (size_t)(m0 + r) * 16 + cg;
    bb[o] = acc0; bd[o] = acc1; lam[o] = acc2;
}

// ---------------------------------------------------------------------------
// Causal depthwise conv1d (K=4) + SiLU, + optional per-head l2norm.
// Reads strided slice of mega-GEMM pre-activations. fp32 out.
// mode: 0 = silu only (v); 1 = + l2norm (k); 2 = + l2norm * DK^-0.5 (q)
// ---------------------------------------------------------------------------
__global__ __launch_bounds__(256) void conv_silu_kernel(
    const float* __restrict__ xin, int ldx, int coloff,
    const float* __restrict__ w, float* __restrict__ yout, int mode)
{
    const int bt  = blockIdx.x;
    const int t   = bt & (T_ - 1);
    const int tid = threadIdx.x;
    const float* xr = xin + (size_t)bt * ldx + coloff;

    float val[8];
    #pragma unroll
    for (int jj = 0; jj < 8; ++jj) {
        int c = tid + 256 * jj;
        float4 wc = *(const float4*)(w + (size_t)c * 4);
        const float* xc = xr + c;
        float acc = wc.w * xc[0];
        if (t >= 1) acc += wc.z * xc[-ldx];
        if (t >= 2) acc += wc.y * xc[-2 * ldx];
        if (t >= 3) acc += wc.x * xc[-3 * ldx];
        val[jj] = acc * sigmoidf_(acc);
    }

    if (mode > 0) {
        __shared__ float red[4][8];
        const int wv = tid >> 6;
        #pragma unroll
        for (int jj = 0; jj < 8; ++jj) {
            float v2 = val[jj] * val[jj];
            #pragma unroll
            for (int m = 1; m < 64; m <<= 1) v2 += __shfl_xor(v2, m);
            if ((tid & 63) == 0) red[wv][jj] = v2;
        }
        __syncthreads();
        const int wb = (tid >> 7) * 2;
        #pragma unroll
        for (int jj = 0; jj < 8; ++jj) {
            float ss = red[wb][jj] + red[wb + 1][jj];
            float sc = rsqrtf(ss + 1e-6f);
            if (mode == 2) sc *= 0.08838834764831845f;     // DK^-0.5
            val[jj] *= sc;
        }
    }

    const size_t row = (size_t)bt * HID_;
    #pragma unroll
    for (int jj = 0; jj < 8; ++jj)
        yout[row + tid + 256 * jj] = val[jj];
}

// ---------------------------------------------------------------------------
// Decay gates, in place on gfgs [M,4096] (cols 0..2047 = gf, 2048.. = gs):
// x <- exp(-exp(A_log[h]) * softplus(x + dtb))
// ---------------------------------------------------------------------------
__global__ __launch_bounds__(256) void decay_gate_kernel(
    float* gfgs, const float* __restrict__ A_log,
    const float* __restrict__ dt_bias)
{
    size_t i = (size_t)blockIdx.x * 256 + threadIdx.x;   // over M*2048
    int c = (int)(i & (HID_ - 1));
    size_t m = i >> 11;
    int h = c >> 7;
    float* pf = gfgs + m * 4096 + c;
    float* ps = pf + 2048;
    float na = -__expf(A_log[h]);
    float db = dt_bias[c];
    float xf = *pf + db;
    float xs = *ps + db;
    float spf = (xf > 20.0f) ? xf : log1pf(__expf(xf));
    float sps = (xs > 20.0f) ? xs : log1pf(__expf(xs));
    *pf = __expf(na * spf);
    *ps = __expf(na * sps);
}

// ---------------------------------------------------------------------------
// Dual-state gated delta-rule recurrence, v4: fp32 q/k (no cvt on the hot
// path), swizzled LDS layout (2-way max bank aliasing = free), unrolled
// 16-step loop, DPP row16 reductions.
// Grid: 512 blocks: bx = sv*32 + bh;  bh = b*16+h, sv = s*8+vc.
// Block: 256 threads = 4 waves; wave = 4 cols x 16 ksegs (8 k-chan each).
// LDS slot layout per row (128 floats): slot l<16 holds channels 8l..8l+3,
// slot l>=16 holds 8(l-16)+4..8(l-16)+7  -> each b128 read is 2-way/bank.
// ---------------------------------------------------------------------------
__global__ __launch_bounds__(256) void fkda_kernel(
    const float* __restrict__ qp, const float* __restrict__ kp,
    const float* __restrict__ vp, const float* __restrict__ egf,
    const float* __restrict__ egs, int ldeg,
    const float* __restrict__ bbp, const float* __restrict__ bdp,
    float* __restrict__ ofp, float* __restrict__ osp)
{
    const int bx = blockIdx.x;
    const int bh = bx & 31;
    const int sv = bx >> 5;
    const int b  = bh >> 4;
    const int h  = bh & 15;
    const int s  = sv >> 3;
    const int vc = sv & 7;

    const float* eg = s ? egs : egf;
    float*       op = s ? osp : ofp;
    const float  bsign = s ? -1.0f : 1.0f;

    const int tid  = threadIdx.x;
    const int lane = tid & 63;
    const int w    = tid >> 6;
    const int kseg = lane & 15;
    const int colb = w * 4 + (lane >> 4);

    const size_t base  = (size_t)b * T_ * HID_ + (size_t)h * DK_;
    const size_t baseg = (size_t)b * T_ * ldeg + (size_t)h * DK_;

    __shared__ float EG[TS_ * 128];     // 8 KB each
    __shared__ float KK[TS_ * 128];
    __shared__ float QQ[TS_ * 128];
    __shared__ float VV[TS_ * 16];
    __shared__ float OT[TS_ * 16];
    __shared__ float BT[TS_];

    float S[8];
    #pragma unroll
    for (int j = 0; j < 8; ++j) S[j] = 0.0f;

    // staging lane map: flat word W = n*256 + 4*lane must hold row tt's
    // swizzled slot; lane fetches the matching global channel.
    const int l5  = lane & 31;
    const int ttl = lane >> 5;
    const int cg  = (l5 < 16) ? (l5 * 8) : ((l5 - 16) * 8 + 4);
    const int sl  = kseg * 4;    // read slot word base

    for (int t0 = 0; t0 < T_; t0 += TS_) {
        // ---- stage tile (all via global_load_lds, 16B/lane) ----
        #pragma unroll
        for (int i = 0; i < 2; ++i) {
            int n  = w * 2 + i;
            int tt = n * 2 + ttl;
            size_t rq = base  + (size_t)(t0 + tt) * HID_ + cg;
            size_t rg = baseg + (size_t)(t0 + tt) * ldeg + cg;
            ldg_to_lds16(eg + rg, EG + n * 256);
            ldg_to_lds16(kp + rq, KK + n * 256);
            ldg_to_lds16(qp + rq, QQ + n * 256);
        }
        if (tid < 64) {       // V: 16t x 16cols fp32
            int tt = tid >> 2, vo = (tid & 3) * 4;
            size_t g = base + (size_t)(t0 + tt) * HID_ + vc * 16 + vo;
            ((float4*)VV)[tid] = *(const float4*)(vp + g);
        }
        if (tid < TS_) {
            size_t gi = ((size_t)b * T_ + t0 + tid) * H_ + h;
            BT[tid] = sigmoidf_(bbp[gi] + bsign * bdp[gi]);
        }
        __syncthreads();

        // ---- 16 sequential steps ----
        #pragma unroll
        for (int tt = 0; tt < TS_; ++tt) {
            float e[8], kf[8], qf[8];
            *(float4*)&e[0]  = *(const float4*)(EG + tt * 128 + sl);
            *(float4*)&e[4]  = *(const float4*)(EG + tt * 128 + 64 + sl);
            *(float4*)&kf[0] = *(const float4*)(KK + tt * 128 + sl);
            *(float4*)&kf[4] = *(const float4*)(KK + tt * 128 + 64 + sl);
            *(float4*)&qf[0] = *(const float4*)(QQ + tt * 128 + sl);
            *(float4*)&qf[4] = *(const float4*)(QQ + tt * 128 + 64 + sl);
            float vcol = VV[tt * 16 + colb];
            float btv  = BT[tt];

            float p0 = 0.0f, p1 = 0.0f;
            #pragma unroll
            for (int j = 0; j < 8; j += 2) {
                S[j]     *= e[j];     p0 += kf[j]     * S[j];
                S[j + 1] *= e[j + 1]; p1 += kf[j + 1] * S[j + 1];
            }
            float p = row16_allreduce(p0 + p1);

            float u = btv * (vcol - p);

            float o0 = 0.0f, o1 = 0.0f;
            #pragma unroll
            for (int j = 0; j < 8; j += 2) {
                S[j]     += kf[j]     * u; o0 += qf[j]     * S[j];
                S[j + 1] += kf[j + 1] * u; o1 += qf[j + 1] * S[j + 1];
            }
            float oo = row16_allreduce(o0 + o1);

            if (kseg == 0) OT[tt * 16 + colb] = oo;
        }
        __syncthreads();

        // ---- flush 16x16 outputs ----
        if (tid < 64) {
            int tt = tid >> 2, vo = (tid & 3) * 4;
            size_t g = base + (size_t)(t0 + tt) * HID_ + vc * 16 + vo;
            *(float4*)(op + g) = ((const float4*)OT)[tid];
        }
    }
}

// ---------------------------------------------------------------------------
// o = lam*o_f + (1-lam)*o_s -> per-head RMSNorm * onorm_w -> * sigmoid(gate)
// ---------------------------------------------------------------------------
__global__ __launch_bounds__(256) void mix_norm_gate_kernel(
    const float* of, const float* os, const float* lam_pre,
    const float* gate, const float* onorm_w, bf16* outp)
{
    const int bt  = blockIdx.x;
    const int tid = threadIdx.x;
    const size_t row = (size_t)bt * HID_;

    float val[8];
    #pragma unroll
    for (int jj = 0; jj < 8; ++jj) {
        int c = tid + 256 * jj;
        int h = c >> 7;
        float l = sigmoidf_(lam_pre[(size_t)bt * H_ + h]);
        val[jj] = l * of[row + c] + (1.0f - l) * os[row + c];
    }

    __shared__ float red[4][8];
    const int wv = tid >> 6;
    #pragma unroll
    for (int jj = 0; jj < 8; ++jj) {
        float v2 = val[jj] * val[jj];
        #pragma unroll
        for (int m = 1; m < 64; m <<= 1) v2 += __shfl_xor(v2, m);
        if ((tid & 63) == 0) red[wv][jj] = v2;
    }
    __syncthreads();
    const int wb = (tid >> 7) * 2;
    #pragma unroll
    for (int jj = 0; jj < 8; ++jj) {
        int c = tid + 256 * jj;
        float ss   = red[wb][jj] + red[wb + 1][jj];
        float mean = ss * (1.0f / 128.0f);
        float sc   = rsqrtf(mean + 1e-5f) * onorm_w[c & 127];
        float g    = sigmoidf_(gate[row + c]);
        outp[row + c] = (bf16)(val[jj] * sc * g);
    }
}

// ---------------------------------------------------------------------------
extern "C" void kernel_launch(void* const* d_in, const int* in_sizes, int n_in,
                              void* d_out, int out_size, void* d_ws, size_t ws_size,
                              hipStream_t stream) {
    const float* x       = (const float*)d_in[0];
    const float* Wq      = (const float*)d_in[1];
    const float* Wk      = (const float*)d_in[2];
    const float* Wv      = (const float*)d_in[3];
    const float* conv_wq = (const float*)d_in[4];
    const float* conv_wk = (const float*)d_in[5];
    const float* conv_wv = (const float*)d_in[6];
    const float* Wgb1    = (const float*)d_in[7];
    const float* Wgb2    = (const float*)d_in[8];
    const float* Wgd1    = (const float*)d_in[9];
    const float* Wgd2    = (const float*)d_in[10];
    const float* Wbb     = (const float*)d_in[11];
    const float* Wbd     = (const float*)d_in[12];
    const float* Wlam    = (const float*)d_in[13];
    const float* A_log   = (const float*)d_in[14];
    const float* dt_bias = (const float*)d_in[15];
    const float* Wg1     = (const float*)d_in[16];
    const float* Wg2     = (const float*)d_in[17];
    const float* bg2     = (const float*)d_in[18];
    const float* onorm_w = (const float*)d_in[19];
    const float* Wo      = (const float*)d_in[20];
    float* out = (float*)d_out;

    const size_t M = (size_t)B_ * T_;   // 2048

    float* ws = (float*)d_ws;
    size_t off = 0;
    auto alloc = [&](size_t nfloats) { float* p = ws + off; off += nfloats; return p; };

    float* bufQKV = alloc(M * 6528);              // mega preacts; later gfgs+gate
    float* wqkvTf = alloc((size_t)6528 * HID_ / 2);  // [6528,2048] bf16; reused
    float* xbf    = alloc(M * HID_ / 2);          // x bf16; later obf
    float* bufQ   = alloc(M * HID_);              // q fp32
    float* bufK   = alloc(M * HID_);              // k fp32
    float* bufV   = alloc(M * HID_);              // v fp32
    float* bufC   = alloc(M * HID_);              // o_f
    float* bufD   = alloc(M * HID_);              // o_s
    float* midbf  = alloc(M * 384 / 2);           // midb bf16
    float* bb     = alloc(M * H_);
    float* bd     = alloc(M * H_);
    float* lamp   = alloc(M * H_);

    bf16* xb    = (bf16*)xbf;
    bf16* obf   = (bf16*)xbf;                     // reuse after mega-gemm
    bf16* wqkvT = (bf16*)wqkvTf;
    bf16* woT   = wqkvT;                          // [2048,2048] after mega-gemm
    bf16* wcat  = wqkvT + (size_t)HID_ * HID_;    // [4096,256]
    bf16* wgate = wcat + (size_t)4096 * 256;      // [2048,128]
    bf16* midb  = (bf16*)midbf;
    float* gfgs = bufQKV;                         // [2048,4096] after conv
    float* bufE = bufQKV + M * 4096;              // gate [2048,2048]

    dim3 blk(256);
    auto gemm = [&](const bf16* A, const bf16* Bt, const float* bias, void* C,
                    int Mm, int Nn, int Kk, int lda, int ldc, int bf16out) {
        dim3 grid(Nn / 128, Mm / 128);
        mfma_gemm_kernel<<<grid, blk, 0, stream>>>(A, Bt, bias, C, Mm, Nn, Kk,
                                                   lda, ldc, bf16out);
    };
    auto tcast = [&](const float* W, bf16* Wt, int Kk, int Nn) {
        tcast_kernel<<<dim3(Nn / 32, Kk / 32), blk, 0, stream>>>(W, Wt, Kk, Nn);
    };

    // 0) cast x to bf16
    cast_bf16_kernel<<<dim3((unsigned)(M * HID_ / 8 / 256)), blk, 0, stream>>>(x, xb);

    // 1) mega projection: [Wq|Wk|Wv|Wgb1|Wgd1|Wg1], N=6528
    tcast(Wq,   wqkvT,                          HID_, HID_);
    tcast(Wk,   wqkvT + (size_t)2048 * HID_,    HID_, HID_);
    tcast(Wv,   wqkvT + (size_t)4096 * HID_,    HID_, HID_);
    tcast(Wgb1, wqkvT + (size_t)6144 * HID_,    HID_, 128);
    tcast(Wgd1, wqkvT + (size_t)6272 * HID_,    HID_, 128);
    tcast(Wg1,  wqkvT + (size_t)6400 * HID_,    HID_, 128);
    gemm(xb, wqkvT, nullptr, bufQKV, (int)M, 6528, HID_, HID_, 6528, 0);

    // 2) conv + silu (+ l2norm), fp32 outputs
    conv_silu_kernel<<<dim3(B_ * T_), blk, 0, stream>>>(bufQKV, 6528, 0,
        conv_wq, bufQ, 2);
    conv_silu_kernel<<<dim3(B_ * T_), blk, 0, stream>>>(bufQKV, 6528, 2048,
        conv_wk, bufK, 1);
    conv_silu_kernel<<<dim3(B_ * T_), blk, 0, stream>>>(bufQKV, 6528, 4096,
        conv_wv, bufV, 0);

    // 3) mid slice -> bf16
    midcast_kernel<<<dim3((unsigned)(M * 96 / 256)), blk, 0, stream>>>(bufQKV, midb);

    // 4) skinny heads bb/bd/lam
    skinny3_kernel<<<dim3((unsigned)(M / 16)), blk, 0, stream>>>(
        x, Wbb, Wbd, Wlam, bb, bd, lamp);

    // 5) build concat weights and run fused gf/gs expand (N=4096, K=256)
    tcast_off_kernel<<<dim3(64, 4), blk, 0, stream>>>(Wgb2, wcat, HID_, 0,    0,   1.0f);
    tcast_off_kernel<<<dim3(64, 4), blk, 0, stream>>>(Wgd2, wcat, HID_, 0,    128, 1.0f);
    tcast_off_kernel<<<dim3(64, 4), blk, 0, stream>>>(Wgb2, wcat, HID_, 2048, 0,   1.0f);
    tcast_off_kernel<<<dim3(64, 4), blk, 0, stream>>>(Wgd2, wcat, HID_, 2048, 128, -1.0f);
    tcast(Wg2, wgate, 128, HID_);
    tcast(Wo,  woT,   HID_, HID_);
    gemm(midb,       wcat,  nullptr, gfgs, (int)M, 4096, 256, 384, 4096, 0);
    gemm(midb + 256, wgate, bg2,     bufE, (int)M, HID_, 128, 384, HID_, 0);

    // 6) decay gates in place on gfgs
    decay_gate_kernel<<<dim3((unsigned)(M * HID_ / 256)), blk, 0, stream>>>(
        gfgs, A_log, dt_bias);

    // 7) dual-state delta-rule recurrence (512 blocks)
    fkda_kernel<<<dim3(512), blk, 0, stream>>>(bufQ, bufK, bufV,
        gfgs, gfgs + 2048, 4096, bb, bd, bufC, bufD);

    // 8) mix + rmsnorm + gate -> bf16
    mix_norm_gate_kernel<<<dim3(B_ * T_), blk, 0, stream>>>(
        bufC, bufD, lamp, bufE, onorm_w, obf);

    // 9) output projection
    gemm(obf, woT, nullptr, out, (int)M, HID_, HID_, HID_, HID_, 0);
}